// Round 1
// 443.555 us; speedup vs baseline: 1.0371x; 1.0371x over previous
//
#include <hip/hip_runtime.h>

// Problem constants
#define BN    2400   // B*N
#define NG    4      // groups
#define DIM   256

// R12: generator GEMM rebuilt as 128x128 tile (BK=64), m97-structure:
//  - BOTH operands pre-packed into MFMA-fragment-major global layout
//    ([t64][kc8][rg4][lane64][8]) so staging is global_load_lds(16) of
//    contiguous 1KB wave chunks (linear dest = linear src, rule #21 trivially
//    satisfied) and every ds_read_b128 is lane-contiguous -> zero bank
//    conflicts by construction.
//  - 4 waves 2x2, each wave 64x64 (4x4 frags), 32 MFMA per barrier pair.
//  - bijective XCD swizzle so each XCD owns a contiguous slab of n-tiles:
//    W slab (~1.3MB) + full qvP (1.2MB) stay L2-resident.
// prep_perm / new prep_flat_frag emit fragment-major WP; prep_flat kept
// unchanged for projection weights. Y layout, p2, proj, final untouched.

typedef __attribute__((ext_vector_type(8))) short bf16x8;
typedef __attribute__((ext_vector_type(4))) short bf16x4;
typedef __attribute__((ext_vector_type(4))) float f32x4;

__device__ __forceinline__ float b2f(unsigned short u) {
    union { unsigned int i; float f; } v; v.i = ((unsigned int)u) << 16; return v.f;
}
__device__ __forceinline__ unsigned short f2b(float f) {
    union { float f; unsigned int i; } v; v.f = f;
    unsigned int x = v.i;
    return (unsigned short)((x + 0x7fffu + ((x >> 16) & 1u)) >> 16);  // RNE
}

__device__ __forceinline__ void glds16(const unsigned short* g, const short* l) {
    __builtin_amdgcn_global_load_lds(
        (const __attribute__((address_space(1))) unsigned int*)(const void*)g,
        (__attribute__((address_space(3))) unsigned int*)(void*)const_cast<short*>(l),
        16, 0, 0);
}

__device__ __forceinline__ void block_stats(float s, float q, float* sRed, int tid,
                                            float inv_n, float& mean, float& istd) {
    #pragma unroll
    for (int off = 32; off > 0; off >>= 1) {
        s += __shfl_down(s, off, 64);
        q += __shfl_down(q, off, 64);
    }
    if ((tid & 63) == 0) { sRed[(tid >> 6) * 2] = s; sRed[(tid >> 6) * 2 + 1] = q; }
    __syncthreads();
    if (tid == 0) {
        float ts = 0.f, tq = 0.f;
        for (int w = 0; w < 4; ++w) { ts += sRed[2 * w]; tq += sRed[2 * w + 1]; }
        float m = ts * inv_n;
        float var = tq * inv_n - m * m;
        sRed[8] = m; sRed[9] = rsqrtf(var + 1e-5f);
    }
    __syncthreads();
    mean = sRed[8]; istd = sRed[9];
}

// ---------------------------------------------------------------------------
// Weight preps. Fragment-major addressing for within-branch out-row n, col k:
//   nt=n>>6, rg=(n>>4)&3, r16=n&15, kc=k>>5, q=(k>>3)&3, j=k&7, lane=r16|(q<<4)
//   elem = (((nt*8+kc)*4+rg)*64+lane)*8 + j
// ---------------------------------------------------------------------------
__global__ __launch_bounds__(256) void prep_perm_kernel(
    const float* __restrict__ wA, const float* __restrict__ bA,
    unsigned short* __restrict__ oA, float* __restrict__ obA,
    const float* __restrict__ wB, const float* __restrict__ bB,
    unsigned short* __restrict__ oB, float* __restrict__ obB)
{
    const float* w = blockIdx.y ? wB : wA;
    const float* b = blockIdx.y ? bB : bA;
    unsigned short* wOut = blockIdx.y ? oB : oA;
    float* bOut = blockIdx.y ? obB : obA;

    const int row_o = blockIdx.x * 4 + (threadIdx.x >> 6);
    const int lane = threadIdx.x & 63;
    const int g = row_o >> 12, d = (row_o >> 6) & 63, c = row_o & 63;
    const int row_i = (g << 12) + c * 64 + d;
    const float4 x = *(const float4*)(w + (size_t)row_i * 256 + lane * 4);
    bf16x4 pk;
    pk[0] = (short)f2b(x.x); pk[1] = (short)f2b(x.y);
    pk[2] = (short)f2b(x.z); pk[3] = (short)f2b(x.w);

    const int k0 = lane * 4;
    const int nt = row_o >> 6, rg = (row_o >> 4) & 3, r16 = row_o & 15;
    const int kc = k0 >> 5, q = (k0 >> 3) & 3, j = k0 & 7;
    const int lp = r16 | (q << 4);
    *(bf16x4*)(wOut + ((((size_t)(nt * 8 + kc) * 4 + rg) * 64 + lp) * 8 + j)) = pk;
    if (lane == 0) bOut[row_o] = b[row_i];
}

// fragment-major pack of s_w / q_w into rows n = 16384 + r of each branch
__global__ __launch_bounds__(256) void prep_flat_frag_kernel(
    const float* __restrict__ a0, unsigned short* __restrict__ o0,
    const float* __restrict__ a1, unsigned short* __restrict__ o1)
{
    const float* src = blockIdx.y ? a1 : a0;
    unsigned short* dst = blockIdx.y ? o1 : o0;
    const int idx = (blockIdx.x * 256 + threadIdx.x) * 8;
    if (idx >= 4096 * 256) return;
    float4 x0 = ((const float4*)(src + idx))[0];
    float4 x1 = ((const float4*)(src + idx))[1];
    bf16x8 v;
    v[0]=(short)f2b(x0.x); v[1]=(short)f2b(x0.y); v[2]=(short)f2b(x0.z); v[3]=(short)f2b(x0.w);
    v[4]=(short)f2b(x1.x); v[5]=(short)f2b(x1.y); v[6]=(short)f2b(x1.z); v[7]=(short)f2b(x1.w);

    const int r = idx >> 8;
    const int k0 = idx & 255;
    const int n = 16384 + r;
    const int nt = n >> 6, rg = (n >> 4) & 3, r16 = n & 15;
    const int kc = k0 >> 5, q = (k0 >> 3) & 3;
    const int lp = r16 | (q << 4);
    *(bf16x8*)(dst + (((size_t)(nt * 8 + kc) * 4 + rg) * 64 + lp) * 8) = v;
}

// flat bf16 cast (kept for projection weights)
__global__ __launch_bounds__(256) void prep_flat_kernel(
    const float* __restrict__ a0, unsigned short* __restrict__ o0, int n0,
    const float* __restrict__ a1, unsigned short* __restrict__ o1, int n1,
    const float* __restrict__ a2, unsigned short* __restrict__ o2, int n2)
{
    const float* src; unsigned short* dst; int n;
    if (blockIdx.y == 0)      { src = a0; dst = o0; n = n0; }
    else if (blockIdx.y == 1) { src = a1; dst = o1; n = n1; }
    else                      { src = a2; dst = o2; n = n2; }
    const int idx = (blockIdx.x * 256 + threadIdx.x) * 8;
    if (idx >= n) return;
    float4 x0 = ((const float4*)(src + idx))[0];
    float4 x1 = ((const float4*)(src + idx))[1];
    bf16x8 v;
    v[0]=(short)f2b(x0.x); v[1]=(short)f2b(x0.y); v[2]=(short)f2b(x0.z); v[3]=(short)f2b(x0.w);
    v[4]=(short)f2b(x1.x); v[5]=(short)f2b(x1.y); v[6]=(short)f2b(x1.z); v[7]=(short)f2b(x1.w);
    *(bf16x8*)(dst + idx) = v;
}

__global__ __launch_bounds__(256) void copy_bias_kernel(
    const float* __restrict__ a0, float* __restrict__ o0,
    const float* __restrict__ a1, float* __restrict__ o1)
{
    const int i = blockIdx.x * 256 + threadIdx.x;
    if (blockIdx.y == 0) o0[i] = a0[i]; else o1[i] = a1[i];
}

// ---------------------------------------------------------------------------
// Pack qv (fp32, BN x 256) into MFMA-A-fragment-major bf16:
// qvP[mt][kc][rg][lane][8] = qv[mt*64 + rg*16 + (lane&15)][kc*32 + (lane>>4)*8 + j]
// ---------------------------------------------------------------------------
__global__ __launch_bounds__(256) void prep_pack_a_kernel(
    const float* __restrict__ qv, unsigned short* __restrict__ qvP)
{
    const int idx = blockIdx.x * 256 + threadIdx.x;   // chunk index
    if (idx >= 38 * 8 * 4 * 64) return;
    const int lane = idx & 63;
    const int rg   = (idx >> 6) & 3;
    const int kc   = (idx >> 8) & 7;
    const int mt   = idx >> 11;
    int row = mt * 64 + rg * 16 + (lane & 15);
    if (row >= BN) row = BN - 1;
    const int col = kc * 32 + (lane >> 4) * 8;
    const float* p = qv + (size_t)row * 256 + col;
    float4 x0 = ((const float4*)p)[0];
    float4 x1 = ((const float4*)p)[1];
    bf16x8 v;
    v[0]=(short)f2b(x0.x); v[1]=(short)f2b(x0.y); v[2]=(short)f2b(x0.z); v[3]=(short)f2b(x0.w);
    v[4]=(short)f2b(x1.x); v[5]=(short)f2b(x1.y); v[6]=(short)f2b(x1.z); v[7]=(short)f2b(x1.w);
    *(bf16x8*)(qvP + (size_t)idx * 8) = v;
}

// ---------------------------------------------------------------------------
// Generator GEMM: C = qv * W^T + bias, bf16 out. 128x128 tile, BK=64,
// 4 waves 2x2 each 64x64 (4x4 fragments). Both operands staged via
// global_load_lds(16) from fragment-major packed buffers; all ds_reads
// lane-contiguous (conflict-free). Bijective XCD swizzle for W/qvP L2 locality.
// ---------------------------------------------------------------------------
__global__ __launch_bounds__(256) void gemm_gen_kernel(
    const unsigned short* __restrict__ qvP,
    const unsigned short* __restrict__ W1, const float* __restrict__ b1,
    unsigned short* __restrict__ C1,
    const unsigned short* __restrict__ W2, const float* __restrict__ b2,
    unsigned short* __restrict__ C2,
    int ySplit, int M, int N)
{
    __shared__ __align__(16) short sAB[2][16][64][8];   // 32 KB: [A/B][chunk][lane][8]

    // XCD-aware bijective swizzle (nwg % 8 == 0 by construction).
    const int flat = blockIdx.y * gridDim.x + blockIdx.x;
    const int nwg = gridDim.x * gridDim.y;
    const int wg = (flat & 7) * (nwg >> 3) + (flat >> 3);
    const int mb = wg % gridDim.x;      // gridDim.x = 19
    const int nb = wg / gridDim.x;

    const bool s2 = (nb >= ySplit);
    const unsigned short* W = s2 ? W2 : W1;
    const float* bias = s2 ? b2 : b1;
    unsigned short* C = s2 ? C2 : C1;
    const int nbb = s2 ? nb - ySplit : nb;

    const int tid = threadIdx.x;
    const int lane = tid & 63;
    const int wave = tid >> 6;
    const int l16 = lane & 15;
    const int quad = lane >> 4;

    const int wmi = wave >> 1;   // wave m half
    const int wni = wave & 1;    // wave n half

    // staging: wave handles src chunk (smi, skci) for both A and B
    const int smi = wave >> 1, skci = wave & 1;
    const unsigned short* aSrc0 = qvP + (size_t)(mb * 2 + smi) * (8 * 4 * 64 * 8);
    const unsigned short* bSrc0 = W   + (size_t)(nbb * 2 + smi) * (8 * 4 * 64 * 8);
    const int cBase = (smi * 2 + skci) * 4;

    f32x4 acc[4][4] = {};

    for (int t = 0; t < 4; ++t) {
        const unsigned short* as = aSrc0 + (size_t)(2 * t + skci) * 2048;
        const unsigned short* bs = bSrc0 + (size_t)(2 * t + skci) * 2048;
        #pragma unroll
        for (int r = 0; r < 4; ++r) {
            glds16(as + r * 512 + lane * 8, &sAB[0][cBase + r][0][0]);
            glds16(bs + r * 512 + lane * 8, &sAB[1][cBase + r][0][0]);
        }
        __syncthreads();   // compiler emits vmcnt(0) drain before barrier
        #pragma unroll
        for (int kci = 0; kci < 2; ++kci) {
            bf16x8 af[4], bfv[4];
            #pragma unroll
            for (int m = 0; m < 4; ++m)
                af[m] = *(const bf16x8*)(&sAB[0][(wmi * 2 + kci) * 4 + m][lane][0]);
            #pragma unroll
            for (int n = 0; n < 4; ++n)
                bfv[n] = *(const bf16x8*)(&sAB[1][(wni * 2 + kci) * 4 + n][lane][0]);
            #pragma unroll
            for (int m = 0; m < 4; ++m)
                #pragma unroll
                for (int n = 0; n < 4; ++n)
                    acc[m][n] = __builtin_amdgcn_mfma_f32_16x16x32_bf16(
                        af[m], bfv[n], acc[m][n], 0, 0, 0);
        }
        __syncthreads();
    }

    const int m0 = mb * 128, n0 = nbb * 128;
    #pragma unroll
    for (int m = 0; m < 4; ++m) {
        const int row = m0 + wmi * 64 + m * 16 + quad * 4;
        #pragma unroll
        for (int n = 0; n < 4; ++n) {
            const int col = n0 + wni * 64 + n * 16 + l16;
            const float bv = bias[col];
            #pragma unroll
            for (int r = 0; r < 4; ++r) {
                if (row + r < M)
                    C[(size_t)(row + r) * N + col] = f2b(acc[m][n][r] + bv);
            }
        }
    }
}

// ---------------------------------------------------------------------------
// Projection GEMM (unchanged): fp32 split-K partials. 64x64 tile.
// ---------------------------------------------------------------------------
__global__ __launch_bounds__(256) void gemm_proj_kernel(
    const unsigned short* __restrict__ A1, const unsigned short* __restrict__ W1,
    float* __restrict__ C1,
    const unsigned short* __restrict__ A2, const unsigned short* __restrict__ W2,
    float* __restrict__ C2,
    int zSplit, int M, int N, int ldK, int kLen)
{
    __shared__ short sA[64][72];
    __shared__ short sB[64][72];

    const int z = blockIdx.z;
    const bool s2 = (z >= zSplit);
    const int zi = s2 ? z - zSplit : z;
    const unsigned short* A = s2 ? A2 : A1;
    const unsigned short* W = s2 ? W2 : W1;
    float* C = (s2 ? C2 : C1) + (size_t)zi * M * N;

    const int m0 = blockIdx.x * 64;
    const int n0 = blockIdx.y * 64;
    const int tid = threadIdx.x;
    const int lane = tid & 63;
    const int wave = tid >> 6;
    const int l16 = lane & 15;
    const int quad = lane >> 4;
    const int wr = (wave >> 1) * 32;
    const int wc = (wave & 1) * 32;

    const int lr = tid >> 2;
    const int lc = (tid & 3) * 16;

    f32x4 acc[2][2] = {};

    const int kbase = zi * kLen;
    for (int k0 = kbase; k0 < kbase + kLen; k0 += 64) {
        {
            const int gr = m0 + lr;
            bf16x8 a0 = {}, a1 = {};
            if (gr < M) {
                const unsigned short* ap = A + (size_t)gr * ldK + k0 + lc;
                a0 = ((const bf16x8*)ap)[0];
                a1 = ((const bf16x8*)ap)[1];
            }
            *(bf16x8*)(&sA[lr][lc])     = a0;
            *(bf16x8*)(&sA[lr][lc + 8]) = a1;
            const unsigned short* wp = W + (size_t)(n0 + lr) * ldK + k0 + lc;
            *(bf16x8*)(&sB[lr][lc])     = ((const bf16x8*)wp)[0];
            *(bf16x8*)(&sB[lr][lc + 8]) = ((const bf16x8*)wp)[1];
        }
        __syncthreads();
        #pragma unroll
        for (int ks = 0; ks < 64; ks += 32) {
            bf16x8 a0 = *(const bf16x8*)(&sA[wr + l16][ks + quad * 8]);
            bf16x8 a1 = *(const bf16x8*)(&sA[wr + 16 + l16][ks + quad * 8]);
            bf16x8 b0 = *(const bf16x8*)(&sB[wc + l16][ks + quad * 8]);
            bf16x8 b1 = *(const bf16x8*)(&sB[wc + 16 + l16][ks + quad * 8]);
            acc[0][0] = __builtin_amdgcn_mfma_f32_16x16x32_bf16(a0, b0, acc[0][0], 0, 0, 0);
            acc[0][1] = __builtin_amdgcn_mfma_f32_16x16x32_bf16(a0, b1, acc[0][1], 0, 0, 0);
            acc[1][0] = __builtin_amdgcn_mfma_f32_16x16x32_bf16(a1, b0, acc[1][0], 0, 0, 0);
            acc[1][1] = __builtin_amdgcn_mfma_f32_16x16x32_bf16(a1, b1, acc[1][1], 0, 0, 0);
        }
        __syncthreads();
    }

    #pragma unroll
    for (int s = 0; s < 2; ++s) {
        #pragma unroll
        for (int u = 0; u < 2; ++u) {
            const int col = n0 + wc + u * 16 + l16;
            #pragma unroll
            for (int r = 0; r < 4; ++r) {
                const int row = m0 + wr + s * 16 + quad * 4 + r;
                if (row < M)
                    C[(size_t)row * N + col] = acc[s][u][r];
            }
        }
    }
}

// ===========================================================================
// Phase-2 device helpers (unchanged).
// ===========================================================================
__device__ __forceinline__ void p2_stage_feats(
    const float* fp, short (*fB)[72], int tid)
{
    const float* p = fp + tid * 8;
    float4 x0 = ((const float4*)p)[0];
    float4 x1 = ((const float4*)p)[1];
    bf16x8 v;
    v[0]=(short)f2b(x0.x); v[1]=(short)f2b(x0.y); v[2]=(short)f2b(x0.z); v[3]=(short)f2b(x0.w);
    v[4]=(short)f2b(x1.x); v[5]=(short)f2b(x1.y); v[6]=(short)f2b(x1.z); v[7]=(short)f2b(x1.w);
    *(bf16x8*)(&fB[tid >> 3][(tid & 7) * 8]) = v;
}

__device__ __forceinline__ void p2_stage_64x64(
    const unsigned short* mp, short (*T)[72], int tid)
{
    const unsigned short* p = mp + tid * 16;
    bf16x8 v0 = ((const bf16x8*)p)[0];
    bf16x8 v1 = ((const bf16x8*)p)[1];
    const int d = tid >> 2, c0 = (tid & 3) * 16;
    *(bf16x8*)(&T[d][c0])     = v0;
    *(bf16x8*)(&T[d][c0 + 8]) = v1;
}

__device__ __forceinline__ void p2_stage_32x32(
    const unsigned short* sp, short (*T)[40], int tid)
{
    *(bf16x4*)(&T[tid >> 3][(tid & 7) * 4]) = *(const bf16x4*)(sp + tid * 4);
}

__device__ __forceinline__ void p2_reg_body(
    short (*fB)[72], short (*Mt)[72], short (*sS)[40], short (*X1T)[40],
    float* sRed, unsigned short* outp, int tid)
{
    const int wave = tid >> 6, lane = tid & 63;
    const int l16 = lane & 15, quad = lane >> 4;

    f32x4 accA[2] = {};
    #pragma unroll
    for (int ks = 0; ks < 64; ks += 32) {
        bf16x8 b = *(const bf16x8*)(&Mt[wave * 16 + l16][ks + quad * 8]);
        #pragma unroll
        for (int mt = 0; mt < 2; ++mt) {
            bf16x8 a = *(const bf16x8*)(&fB[mt * 16 + l16][ks + quad * 8]);
            accA[mt] = __builtin_amdgcn_mfma_f32_16x16x32_bf16(a, b, accA[mt], 0, 0, 0);
        }
    }
    float ls = 0.f, lq = 0.f;
    #pragma unroll
    for (int mt = 0; mt < 2; ++mt)
        #pragma unroll
        for (int r = 0; r < 4; ++r) { float v = accA[mt][r]; ls += v; lq += v * v; }
    float mean, istd;
    block_stats(ls, lq, sRed, tid, 1.0f / 2048.0f, mean, istd);
    #pragma unroll
    for (int mt = 0; mt < 2; ++mt) {
        bf16x4 pk;
        #pragma unroll
        for (int r = 0; r < 4; ++r) {
            float y = (accA[mt][r] - mean) * istd;
            pk[r] = (short)f2b(y > 0.f ? y : 0.f);
        }
        *(bf16x4*)(&X1T[wave * 16 + l16][mt * 16 + quad * 4]) = pk;
    }
    __syncthreads();

    f32x4 accB[2] = {};
    {
        bf16x8 b = *(const bf16x8*)(&X1T[wave * 16 + l16][quad * 8]);
        #pragma unroll
        for (int mt = 0; mt < 2; ++mt) {
            bf16x8 a = *(const bf16x8*)(&sS[mt * 16 + l16][quad * 8]);
            accB[mt] = __builtin_amdgcn_mfma_f32_16x16x32_bf16(a, b, accB[mt], 0, 0, 0);
        }
    }
    ls = 0.f; lq = 0.f;
    #pragma unroll
    for (int mt = 0; mt < 2; ++mt)
        #pragma unroll
        for (int r = 0; r < 4; ++r) { float v = accB[mt][r]; ls += v; lq += v * v; }
    block_stats(ls, lq, sRed, tid, 1.0f / 2048.0f, mean, istd);

    const int d = wave * 16 + l16;
    #pragma unroll
    for (int mt = 0; mt < 2; ++mt)
        #pragma unroll
        for (int r = 0; r < 4; ++r) {
            float y = (accB[mt][r] - mean) * istd;
            outp[(mt * 16 + quad * 4 + r) * 64 + d] = f2b(y > 0.f ? y : 0.f);
        }
}

__device__ __forceinline__ void p2_cls_body(
    short (*fB)[72], short (*Vt)[72], short (*kw)[72], short (*vRM)[72],
    short (*vT)[40], short (*kT)[40], short (*sQ)[40], short (*sSC)[40],
    float* sKB, float* sRed, unsigned short* outp, int tid)
{
    const int wave = tid >> 6, lane = tid & 63;
    const int l16 = lane & 15, quad = lane >> 4;

    f32x4 accA[2] = {};
    #pragma unroll
    for (int ks = 0; ks < 64; ks += 32) {
        bf16x8 b = *(const bf16x8*)(&Vt[wave * 16 + l16][ks + quad * 8]);
        #pragma unroll
        for (int mt = 0; mt < 2; ++mt) {
            bf16x8 a = *(const bf16x8*)(&fB[mt * 16 + l16][ks + quad * 8]);
            accA[mt] = __builtin_amdgcn_mfma_f32_16x16x32_bf16(a, b, accA[mt], 0, 0, 0);
        }
    }
    float ls = 0.f, lq = 0.f;
    #pragma unroll
    for (int mt = 0; mt < 2; ++mt)
        #pragma unroll
        for (int r = 0; r < 4; ++r) { float v = accA[mt][r]; ls += v; lq += v * v; }
    float mean, istd;
    block_stats(ls, lq, sRed, tid, 1.0f / 2048.0f, mean, istd);
    {
        const int d = wave * 16 + l16;
        #pragma unroll
        for (int mt = 0; mt < 2; ++mt) {
            bf16x4 pk;
            #pragma unroll
            for (int r = 0; r < 4; ++r) {
                float y = (accA[mt][r] - mean) * istd;
                unsigned short u = f2b(y > 0.f ? y : 0.f);
                pk[r] = (short)u;
                vRM[mt * 16 + quad * 4 + r][d] = (short)u;
            }
            *(bf16x4*)(&vT[d][mt * 16 + quad * 4]) = pk;
        }
    }
    __syncthreads();

    {   // k[i][p] = kw[i]·v[p] + kb
        const int it = wave >> 1, pt = wave & 1;
        f32x4 accK = {};
        #pragma unroll
        for (int ks = 0; ks < 64; ks += 32) {
            bf16x8 a = *(const bf16x8*)(&kw[it * 16 + l16][ks + quad * 8]);
            bf16x8 b = *(const bf16x8*)(&vRM[pt * 16 + l16][ks + quad * 8]);
            accK = __builtin_amdgcn_mfma_f32_16x16x32_bf16(a, b, accK, 0, 0, 0);
        }
        bf16x4 pk;
        #pragma unroll
        for (int r = 0; r < 4; ++r)
            pk[r] = (short)f2b(accK[r] + sKB[it * 16 + quad * 4 + r]);
        *(bf16x4*)(&kT[pt * 16 + l16][it * 16 + quad * 4]) = pk;
    }
    __syncthreads();

    if (wave < 2) {   // logits + softmax
        f32x4 accL[2] = {};
        bf16x8 a = *(const bf16x8*)(&sQ[wave * 16 + l16][quad * 8]);
        #pragma unroll
        for (int pt = 0; pt < 2; ++pt) {
            bf16x8 b = *(const bf16x8*)(&kT[pt * 16 + l16][quad * 8]);
            accL[pt] = __builtin_amdgcn_mfma_f32_16x16x32_bf16(a, b, accL[pt], 0, 0, 0);
        }
        #pragma unroll
        for (int r = 0; r < 4; ++r) {
            float a0 = accL[0][r] * 0.125f, a1 = accL[1][r] * 0.125f;
            float mx = fmaxf(a0, a1);
            #pragma unroll
            for (int m = 1; m < 16; m <<= 1) mx = fmaxf(mx, __shfl_xor(mx, m, 64));
            a0 = __expf(a0 - mx); a1 = __expf(a1 - mx);
            float sum = a0 + a1;
            #pragma unroll
            for (int m = 1; m < 16; m <<= 1) sum += __shfl_xor(sum, m, 64);
            const float inv_s = 1.0f / sum;
            const int o = wave * 16 + quad * 4 + r;
            sSC[o][l16]      = (short)f2b(a0 * inv_s);
            sSC[o][16 + l16] = (short)f2b(a1 * inv_s);
        }
    }
    __syncthreads();

    f32x4 accB[2] = {};
    {
        bf16x8 b = *(const bf16x8*)(&vT[wave * 16 + l16][quad * 8]);
        #pragma unroll
        for (int mt = 0; mt < 2; ++mt) {
            bf16x8 a = *(const bf16x8*)(&sSC[mt * 16 + l16][quad * 8]);
            accB[mt] = __builtin_amdgcn_mfma_f32_16x16x32_bf16(a, b, accB[mt], 0, 0, 0);
        }
    }
    ls = 0.f; lq = 0.f;
    #pragma unroll
    for (int mt = 0; mt < 2; ++mt)
        #pragma unroll
        for (int r = 0; r < 4; ++r) { float v = accB[mt][r]; ls += v; lq += v * v; }
    block_stats(ls, lq, sRed, tid, 1.0f / 2048.0f, mean, istd);

    const int d = wave * 16 + l16;
    #pragma unroll
    for (int mt = 0; mt < 2; ++mt)
        #pragma unroll
        for (int r = 0; r < 4; ++r) {
            float y = (accB[mt][r] - mean) * istd;
            outp[(mt * 16 + quad * 4 + r) * 64 + d] = f2b(y > 0.f ? y : 0.f);
        }
}

__device__ __forceinline__ void p2_stage_cls(
    const unsigned short* Y2row, const float* kwp, const float* kbp, int g,
    short (*kw)[72], short (*sQ)[40], float* sKB, int tid)
{
    {
        const float* kp = kwp + (size_t)g * 2048 + tid * 8;
        float4 x0 = ((const float4*)kp)[0];
        float4 x1 = ((const float4*)kp)[1];
        bf16x8 v;
        v[0]=(short)f2b(x0.x); v[1]=(short)f2b(x0.y); v[2]=(short)f2b(x0.z); v[3]=(short)f2b(x0.w);
        v[4]=(short)f2b(x1.x); v[5]=(short)f2b(x1.y); v[6]=(short)f2b(x1.z); v[7]=(short)f2b(x1.w);
        *(bf16x8*)(&kw[tid >> 3][(tid & 7) * 8]) = v;
    }
    p2_stage_32x32(Y2row + 16384 + g * 1024, sQ, tid);
    if (tid < 32) sKB[tid] = kbp[g * 32 + tid];
}

// ---------------------------------------------------------------------------
// p2 split kernels (small-ws path)
// ---------------------------------------------------------------------------
__global__ __launch_bounds__(256) void p2_reg_kernel(
    const float* __restrict__ feats, const unsigned short* __restrict__ Y1,
    unsigned short* __restrict__ FMS)
{
    const int t = blockIdx.x, g = blockIdx.y;
    const int tid = threadIdx.x;
    __shared__ short fB[32][72];
    __shared__ short Mt[64][72];
    __shared__ short sS[32][40];
    __shared__ short X1T[64][40];
    __shared__ float sRed[16];

    p2_stage_feats(feats + (size_t)(t * NG + g) * 2048, fB, tid);
    p2_stage_64x64(Y1 + (size_t)t * 20480 + g * 4096, Mt, tid);
    p2_stage_32x32(Y1 + (size_t)t * 20480 + 16384 + g * 1024, sS, tid);
    __syncthreads();
    p2_reg_body(fB, Mt, sS, X1T, sRed, FMS + (size_t)t * 8192 + g * 2048, tid);
}

__global__ __launch_bounds__(256) void p2_cls_kernel(
    const float* __restrict__ feats, const unsigned short* __restrict__ Y2,
    const float* __restrict__ kwp, const float* __restrict__ kbp,
    unsigned short* __restrict__ FC)
{
    const int t = blockIdx.x, g = blockIdx.y;
    const int tid = threadIdx.x;
    __shared__ short fB[32][72];
    __shared__ short Vt[64][72];
    __shared__ short kw[32][72];
    __shared__ short vRM[32][72];
    __shared__ short vT[64][40];
    __shared__ short kT[32][40];
    __shared__ short sQ[32][40];
    __shared__ short sSC[32][40];
    __shared__ float sKB[32];
    __shared__ float sRed[16];

    p2_stage_feats(feats + (size_t)(t * NG + g) * 2048, fB, tid);
    p2_stage_64x64(Y2 + (size_t)t * 20480 + g * 4096, Vt, tid);
    p2_stage_cls(Y2 + (size_t)t * 20480, kwp, kbp, g, kw, sQ, sKB, tid);
    __syncthreads();
    p2_cls_body(fB, Vt, kw, vRM, vT, kT, sQ, sSC, sKB, sRed,
                FC + (size_t)t * 8192 + g * 2048, tid);
}

// ---------------------------------------------------------------------------
// p2 fused kernel (big-ws path)
// ---------------------------------------------------------------------------
__global__ __launch_bounds__(256) void p2_fused_kernel(
    const float* __restrict__ feats,
    const unsigned short* __restrict__ Y1,
    const unsigned short* __restrict__ Y2,
    const float* __restrict__ kwp, const float* __restrict__ kbp,
    unsigned short* __restrict__ FMS, unsigned short* __restrict__ FC)
{
    const int t = blockIdx.x, g = blockIdx.y;
    const int tid = threadIdx.x;
    __shared__ short fB[32][72];
    __shared__ short MtVt[64][72];
    __shared__ short XvT[64][40];
    __shared__ short sSQ[32][40];
    __shared__ short kw[32][72];
    __shared__ short vRM[32][72];
    __shared__ short kT[32][40];
    __shared__ short sSC[32][40];
    __shared__ float sKB[32];
    __shared__ float sRed[16];

    p2_stage_feats(feats + (size_t)(t * NG + g) * 2048, fB, tid);
    p2_stage_64x64(Y1 + (size_t)t * 20480 + g * 4096, MtVt, tid);
    p2_stage_32x32(Y1 + (size_t)t * 20480 + 16384 + g * 1024, sSQ, tid);
    __syncthreads();
    p2_reg_body(fB, MtVt, sSQ, XvT, sRed, FMS + (size_t)t * 8192 + g * 2048, tid);
    __syncthreads();
    p2_stage_64x64(Y2 + (size_t)t * 20480 + g * 4096, MtVt, tid);
    p2_stage_cls(Y2 + (size_t)t * 20480, kwp, kbp, g, kw, sSQ, sKB, tid);
    __syncthreads();
    p2_cls_body(fB, MtVt, kw, vRM, XvT, kT, sSQ, sSC, sKB, sRed,
                FC + (size_t)t * 8192 + g * 2048, tid);
}

// ---------------------------------------------------------------------------
// Final: reduce split-K=8 partials, residual add, affine LN over 256, fp32 out.
// ---------------------------------------------------------------------------
__global__ __launch_bounds__(256) void final_ln_kernel(
    const float* __restrict__ qv,
    const float* __restrict__ MSP, const float* __restrict__ CLP,
    const float* __restrict__ Wv_b, const float* __restrict__ Wv2_b,
    const float* __restrict__ lnA_w, const float* __restrict__ lnA_b,
    const float* __restrict__ lnB_w, const float* __restrict__ lnB_b,
    float* __restrict__ out)
{
    __shared__ float sRed[16];
    const int t = blockIdx.x;
    const int br = blockIdx.y;
    const int c = threadIdx.x;
    const float* P = br ? CLP : MSP;
    const float* bias = br ? Wv2_b : Wv_b;
    const float* lw = br ? lnB_w : lnA_w;
    const float* lb = br ? lnB_b : lnA_b;

    float x = qv[t * 256 + c] + bias[c];
    #pragma unroll
    for (int s = 0; s < 8; ++s) x += P[(size_t)s * (BN * 256) + t * 256 + c];

    float mean, istd;
    block_stats(x, x * x, sRed, c, 1.0f / 256.0f, mean, istd);
    out[(size_t)br * (BN * 256) + t * 256 + c] = (x - mean) * istd * lw[c] + lb[c];
}

// ---------------------------------------------------------------------------
extern "C" void kernel_launch(void* const* d_in, const int* in_sizes, int n_in,
                              void* d_out, int out_size, void* d_ws, size_t ws_size,
                              hipStream_t stream) {
    const float* feats = (const float*)d_in[0];
    const float* qv    = (const float*)d_in[1];
    const float* m_w   = (const float*)d_in[7];
    const float* m_b   = (const float*)d_in[8];
    const float* s_w   = (const float*)d_in[9];
    const float* s_b   = (const float*)d_in[10];
    const float* q_w   = (const float*)d_in[11];
    const float* q_b   = (const float*)d_in[12];
    const float* v_w   = (const float*)d_in[13];
    const float* v_b   = (const float*)d_in[14];
    const float* k_w   = (const float*)d_in[15];
    const float* k_b   = (const float*)d_in[16];
    const float* Wv_w  = (const float*)d_in[17];
    const float* Wv_b  = (const float*)d_in[18];
    const float* Wv2_w = (const float*)d_in[19];
    const float* Wv2_b = (const float*)d_in[20];
    const float* lnA_w = (const float*)d_in[21];
    const float* lnA_b = (const float*)d_in[22];
    const float* lnB_w = (const float*)d_in[23];
    const float* lnB_b = (const float*)d_in[24];

    char* ws = (char*)d_ws;
    const dim3 blk(256);

    if (ws_size >= 275251200ull) {
        // ===== BIG path (275.3 MB) =====
        unsigned short* Y1 = (unsigned short*)(ws);
        unsigned short* Y2 = (unsigned short*)(ws + 98304000);
        unsigned short* W1   = (unsigned short*)(ws + 196608000);
        unsigned short* W2   = (unsigned short*)(ws + 196608000 + 10485760);
        unsigned short* qvP  = (unsigned short*)(ws + 196608000 + 20971520);  // 1,245,184 B
        float* b1 = (float*)(ws + 196608000 + 22216704);
        float* b2 = (float*)(ws + 196608000 + 22298624);
        unsigned short* FMS = (unsigned short*)(ws + 196608000);
        unsigned short* FC  = (unsigned short*)(ws + 235929600);
        unsigned short* WvB  = (unsigned short*)(ws + 98304000);
        unsigned short* Wv2B = (unsigned short*)(ws + 98304000 + 4194304);
        float* MSP = (float*)(ws);
        float* CLP = (float*)(ws + 19660800);

        prep_perm_kernel<<<dim3(4096, 2), blk, 0, stream>>>(m_w, m_b, W1, b1,
                                                            v_w, v_b, W2, b2);
        prep_flat_frag_kernel<<<dim3(512, 2), blk, 0, stream>>>(s_w, W1, q_w, W2);
        prep_pack_a_kernel<<<304, blk, 0, stream>>>(qv, qvP);
        copy_bias_kernel<<<dim3(16, 2), blk, 0, stream>>>(s_b, b1 + 16384, q_b, b2 + 16384);
        gemm_gen_kernel<<<dim3(19, 320), blk, 0, stream>>>(
            qvP, W1, b1, Y1, W2, b2, Y2, 160, BN, 20480);
        p2_fused_kernel<<<dim3(BN, NG), blk, 0, stream>>>(
            feats, Y1, Y2, k_w, k_b, FMS, FC);
        prep_flat_kernel<<<dim3(1024, 2), blk, 0, stream>>>(
            Wv_w, WvB, 256 * 8192, Wv2_w, Wv2B, 256 * 8192, nullptr, nullptr, 0);
        gemm_proj_kernel<<<dim3(38, 4, 16), blk, 0, stream>>>(
            FMS, WvB, MSP, FC, Wv2B, CLP, 8, BN, 256, 8192, 1024);
        final_ln_kernel<<<dim3(BN, 2), blk, 0, stream>>>(
            qv, MSP, CLP, Wv_b, Wv2_b, lnA_w, lnA_b, lnB_w, lnB_b, (float*)d_out);
    } else {
        // ===== SMALL path (176.9 MB fallback) =====
        unsigned short* Y1  = (unsigned short*)(ws);
        unsigned short* FMS = (unsigned short*)(ws + 98304000);
        unsigned short* FC  = (unsigned short*)(ws + 137625600);
        unsigned short* W1   = (unsigned short*)(ws + 137625600);
        unsigned short* W2   = (unsigned short*)(ws + 137625600 + 10485760);
        unsigned short* qvP  = (unsigned short*)(ws + 137625600 + 20971520);
        float* b1 = (float*)(ws + 137625600 + 22216704);
        float* b2 = (float*)(ws + 137625600 + 22298624);
        float* MSP = (float*)(ws);
        float* CLP = (float*)(ws + 19660800);
        unsigned short* WvB  = (unsigned short*)(ws + 39321600);
        unsigned short* Wv2B = (unsigned short*)(ws + 43515904);

        prep_perm_kernel<<<dim3(4096, 2), blk, 0, stream>>>(m_w, m_b, W1, b1,
                                                            v_w, v_b, W2, b2);
        prep_flat_frag_kernel<<<dim3(512, 2), blk, 0, stream>>>(s_w, W1, q_w, W2);
        prep_pack_a_kernel<<<304, blk, 0, stream>>>(qv, qvP);
        copy_bias_kernel<<<dim3(16, 2), blk, 0, stream>>>(s_b, b1 + 16384, q_b, b2 + 16384);
        gemm_gen_kernel<<<dim3(19, 160), blk, 0, stream>>>(
            qvP, W1, b1, Y1, W1, b1, Y1, 160, BN, 20480);
        p2_reg_kernel<<<dim3(BN, NG), blk, 0, stream>>>(feats, Y1, FMS);
        gemm_gen_kernel<<<dim3(19, 160), blk, 0, stream>>>(
            qvP, W2, b2, Y1, W2, b2, Y1, 160, BN, 20480);
        p2_cls_kernel<<<dim3(BN, NG), blk, 0, stream>>>(feats, Y1, k_w, k_b, FC);
        prep_flat_kernel<<<dim3(1024, 2), blk, 0, stream>>>(
            Wv_w, WvB, 256 * 8192, Wv2_w, Wv2B, 256 * 8192, nullptr, nullptr, 0);
        gemm_proj_kernel<<<dim3(38, 4, 8), blk, 0, stream>>>(
            FMS, WvB, MSP, FMS, WvB, MSP, 8, BN, 256, 8192, 1024);
        gemm_proj_kernel<<<dim3(38, 4, 8), blk, 0, stream>>>(
            FC, Wv2B, CLP, FC, Wv2B, CLP, 8, BN, 256, 8192, 1024);
        final_ln_kernel<<<dim3(BN, 2), blk, 0, stream>>>(
            qv, MSP, CLP, Wv_b, Wv2_b, lnA_w, lnA_b, lnB_w, lnB_b, (float*)d_out);
    }
}

// Round 2
// 417.468 us; speedup vs baseline: 1.1019x; 1.0625x over previous
//
#include <hip/hip_runtime.h>

// Problem constants
#define BN    2400   // B*N
#define NG    4      // groups
#define DIM   256

// R13: generator GEMM pipeline rework.
//  - A-fragments read DIRECTLY from fragment-major qvP (coalesced 1KB wave
//    loads, L1/L2-hot, compiler-counted vmcnt -> no barrier coupling).
//  - B double-buffered in LDS (2 x 16KB), stage for tile t+1 issued BEFORE
//    compute of tile t (T3-minimum 2-phase): the implicit vmcnt(0) at the
//    end-of-iter barrier then waits on ~32-MFMA-old loads.
//  - Epilogue: acc -> padded LDS [128][132] (conflict-free ds_write_b16),
//    then full-row coalesced stores (16B/lane, 4 x 256B per wave-inst)
//    replacing 64 scalar 2B stores/thread.
// prep/p2/proj/final unchanged from R12.

typedef __attribute__((ext_vector_type(8))) short bf16x8;
typedef __attribute__((ext_vector_type(4))) short bf16x4;
typedef __attribute__((ext_vector_type(4))) float f32x4;

__device__ __forceinline__ float b2f(unsigned short u) {
    union { unsigned int i; float f; } v; v.i = ((unsigned int)u) << 16; return v.f;
}
__device__ __forceinline__ unsigned short f2b(float f) {
    union { float f; unsigned int i; } v; v.f = f;
    unsigned int x = v.i;
    return (unsigned short)((x + 0x7fffu + ((x >> 16) & 1u)) >> 16);  // RNE
}

__device__ __forceinline__ void glds16(const unsigned short* g, const short* l) {
    __builtin_amdgcn_global_load_lds(
        (const __attribute__((address_space(1))) unsigned int*)(const void*)g,
        (__attribute__((address_space(3))) unsigned int*)(void*)const_cast<short*>(l),
        16, 0, 0);
}

__device__ __forceinline__ void block_stats(float s, float q, float* sRed, int tid,
                                            float inv_n, float& mean, float& istd) {
    #pragma unroll
    for (int off = 32; off > 0; off >>= 1) {
        s += __shfl_down(s, off, 64);
        q += __shfl_down(q, off, 64);
    }
    if ((tid & 63) == 0) { sRed[(tid >> 6) * 2] = s; sRed[(tid >> 6) * 2 + 1] = q; }
    __syncthreads();
    if (tid == 0) {
        float ts = 0.f, tq = 0.f;
        for (int w = 0; w < 4; ++w) { ts += sRed[2 * w]; tq += sRed[2 * w + 1]; }
        float m = ts * inv_n;
        float var = tq * inv_n - m * m;
        sRed[8] = m; sRed[9] = rsqrtf(var + 1e-5f);
    }
    __syncthreads();
    mean = sRed[8]; istd = sRed[9];
}

// ---------------------------------------------------------------------------
// Weight preps. Fragment-major addressing for within-branch out-row n, col k:
//   nt=n>>6, rg=(n>>4)&3, r16=n&15, kc=k>>5, q=(k>>3)&3, j=k&7, lane=r16|(q<<4)
//   elem = (((nt*8+kc)*4+rg)*64+lane)*8 + j
// ---------------------------------------------------------------------------
__global__ __launch_bounds__(256) void prep_perm_kernel(
    const float* __restrict__ wA, const float* __restrict__ bA,
    unsigned short* __restrict__ oA, float* __restrict__ obA,
    const float* __restrict__ wB, const float* __restrict__ bB,
    unsigned short* __restrict__ oB, float* __restrict__ obB)
{
    const float* w = blockIdx.y ? wB : wA;
    const float* b = blockIdx.y ? bB : bA;
    unsigned short* wOut = blockIdx.y ? oB : oA;
    float* bOut = blockIdx.y ? obB : obA;

    const int row_o = blockIdx.x * 4 + (threadIdx.x >> 6);
    const int lane = threadIdx.x & 63;
    const int g = row_o >> 12, d = (row_o >> 6) & 63, c = row_o & 63;
    const int row_i = (g << 12) + c * 64 + d;
    const float4 x = *(const float4*)(w + (size_t)row_i * 256 + lane * 4);
    bf16x4 pk;
    pk[0] = (short)f2b(x.x); pk[1] = (short)f2b(x.y);
    pk[2] = (short)f2b(x.z); pk[3] = (short)f2b(x.w);

    const int k0 = lane * 4;
    const int nt = row_o >> 6, rg = (row_o >> 4) & 3, r16 = row_o & 15;
    const int kc = k0 >> 5, q = (k0 >> 3) & 3, j = k0 & 7;
    const int lp = r16 | (q << 4);
    *(bf16x4*)(wOut + ((((size_t)(nt * 8 + kc) * 4 + rg) * 64 + lp) * 8 + j)) = pk;
    if (lane == 0) bOut[row_o] = b[row_i];
}

// fragment-major pack of s_w / q_w into rows n = 16384 + r of each branch
__global__ __launch_bounds__(256) void prep_flat_frag_kernel(
    const float* __restrict__ a0, unsigned short* __restrict__ o0,
    const float* __restrict__ a1, unsigned short* __restrict__ o1)
{
    const float* src = blockIdx.y ? a1 : a0;
    unsigned short* dst = blockIdx.y ? o1 : o0;
    const int idx = (blockIdx.x * 256 + threadIdx.x) * 8;
    if (idx >= 4096 * 256) return;
    float4 x0 = ((const float4*)(src + idx))[0];
    float4 x1 = ((const float4*)(src + idx))[1];
    bf16x8 v;
    v[0]=(short)f2b(x0.x); v[1]=(short)f2b(x0.y); v[2]=(short)f2b(x0.z); v[3]=(short)f2b(x0.w);
    v[4]=(short)f2b(x1.x); v[5]=(short)f2b(x1.y); v[6]=(short)f2b(x1.z); v[7]=(short)f2b(x1.w);

    const int r = idx >> 8;
    const int k0 = idx & 255;
    const int n = 16384 + r;
    const int nt = n >> 6, rg = (n >> 4) & 3, r16 = n & 15;
    const int kc = k0 >> 5, q = (k0 >> 3) & 3;
    const int lp = r16 | (q << 4);
    *(bf16x8*)(dst + (((size_t)(nt * 8 + kc) * 4 + rg) * 64 + lp) * 8) = v;
}

// flat bf16 cast (kept for projection weights)
__global__ __launch_bounds__(256) void prep_flat_kernel(
    const float* __restrict__ a0, unsigned short* __restrict__ o0, int n0,
    const float* __restrict__ a1, unsigned short* __restrict__ o1, int n1,
    const float* __restrict__ a2, unsigned short* __restrict__ o2, int n2)
{
    const float* src; unsigned short* dst; int n;
    if (blockIdx.y == 0)      { src = a0; dst = o0; n = n0; }
    else if (blockIdx.y == 1) { src = a1; dst = o1; n = n1; }
    else                      { src = a2; dst = o2; n = n2; }
    const int idx = (blockIdx.x * 256 + threadIdx.x) * 8;
    if (idx >= n) return;
    float4 x0 = ((const float4*)(src + idx))[0];
    float4 x1 = ((const float4*)(src + idx))[1];
    bf16x8 v;
    v[0]=(short)f2b(x0.x); v[1]=(short)f2b(x0.y); v[2]=(short)f2b(x0.z); v[3]=(short)f2b(x0.w);
    v[4]=(short)f2b(x1.x); v[5]=(short)f2b(x1.y); v[6]=(short)f2b(x1.z); v[7]=(short)f2b(x1.w);
    *(bf16x8*)(dst + idx) = v;
}

__global__ __launch_bounds__(256) void copy_bias_kernel(
    const float* __restrict__ a0, float* __restrict__ o0,
    const float* __restrict__ a1, float* __restrict__ o1)
{
    const int i = blockIdx.x * 256 + threadIdx.x;
    if (blockIdx.y == 0) o0[i] = a0[i]; else o1[i] = a1[i];
}

// ---------------------------------------------------------------------------
// Pack qv (fp32, BN x 256) into MFMA-A-fragment-major bf16:
// qvP[mt][kc][rg][lane][8] = qv[mt*64 + rg*16 + (lane&15)][kc*32 + (lane>>4)*8 + j]
// ---------------------------------------------------------------------------
__global__ __launch_bounds__(256) void prep_pack_a_kernel(
    const float* __restrict__ qv, unsigned short* __restrict__ qvP)
{
    const int idx = blockIdx.x * 256 + threadIdx.x;   // chunk index
    if (idx >= 38 * 8 * 4 * 64) return;
    const int lane = idx & 63;
    const int rg   = (idx >> 6) & 3;
    const int kc   = (idx >> 8) & 7;
    const int mt   = idx >> 11;
    int row = mt * 64 + rg * 16 + (lane & 15);
    if (row >= BN) row = BN - 1;
    const int col = kc * 32 + (lane >> 4) * 8;
    const float* p = qv + (size_t)row * 256 + col;
    float4 x0 = ((const float4*)p)[0];
    float4 x1 = ((const float4*)p)[1];
    bf16x8 v;
    v[0]=(short)f2b(x0.x); v[1]=(short)f2b(x0.y); v[2]=(short)f2b(x0.z); v[3]=(short)f2b(x0.w);
    v[4]=(short)f2b(x1.x); v[5]=(short)f2b(x1.y); v[6]=(short)f2b(x1.z); v[7]=(short)f2b(x1.w);
    *(bf16x8*)(qvP + (size_t)idx * 8) = v;
}

// ---------------------------------------------------------------------------
// Generator GEMM: C = qv * W^T + bias, bf16 out. 128x128 tile, BK=64,
// 4 waves 2x2 each 64x64 (4x4 fragments).
// A direct from qvP (global, fragment-major); B double-buffered in LDS via
// global_load_lds(16) with prefetch-before-compute; LDS-coalesced epilogue.
// ---------------------------------------------------------------------------
__global__ __launch_bounds__(256) void gemm_gen_kernel(
    const unsigned short* __restrict__ qvP,
    const unsigned short* __restrict__ W1, const float* __restrict__ b1,
    unsigned short* __restrict__ C1,
    const unsigned short* __restrict__ W2, const float* __restrict__ b2,
    unsigned short* __restrict__ C2,
    int ySplit, int M, int N)
{
    // union: main loop 2 x 16KB B buffers; epilogue 128 x 132 bf16 C tile
    __shared__ __align__(16) char smem[33792];
    short (*sB)[16][64][8] = (short (*)[16][64][8])smem;
    short (*sC)[132]       = (short (*)[132])smem;

    // XCD-aware bijective swizzle (nwg % 8 == 0 by construction).
    const int flat = blockIdx.y * gridDim.x + blockIdx.x;
    const int nwg = gridDim.x * gridDim.y;
    const int wg = (flat & 7) * (nwg >> 3) + (flat >> 3);
    const int mb = wg % gridDim.x;      // gridDim.x = 19
    const int nb = wg / gridDim.x;

    const bool s2 = (nb >= ySplit);
    const unsigned short* Wp = s2 ? W2 : W1;
    const float* bias = s2 ? b2 : b1;
    unsigned short* C = s2 ? C2 : C1;
    const int nbb = s2 ? nb - ySplit : nb;

    const int tid = threadIdx.x;
    const int lane = tid & 63;
    const int wave = tid >> 6;
    const int l16 = lane & 15;
    const int quad = lane >> 4;
    const int wmi = wave >> 1;   // wave m half
    const int wni = wave & 1;    // wave n half

    // B staging assignment: wave covers (ntl, kcl), 4 rg chunks of 1KB
    const int ntl = wave >> 1, kcl = wave & 1;
    const unsigned short* bSrc = Wp + (size_t)(nbb * 2 + ntl) * 16384;
    // A direct base for this wave's m-half
    const unsigned short* aW = qvP + (size_t)(mb * 2 + wmi) * 16384;

    f32x4 acc[4][4] = {};

    // prologue: stage B tile t=0 into buf 0
    #pragma unroll
    for (int r = 0; r < 4; ++r)
        glds16(bSrc + ((size_t)(0 + kcl) * 4 + r) * 512 + lane * 8,
               &sB[0][(ntl * 2 + kcl) * 4 + r][0][0]);
    __syncthreads();

    int buf = 0;
    for (int t = 0; t < 4; ++t) {
        // prefetch next B tile BEFORE compute (latency hides under MFMA)
        if (t < 3) {
            #pragma unroll
            for (int r = 0; r < 4; ++r)
                glds16(bSrc + ((size_t)(2 * (t + 1) + kcl) * 4 + r) * 512 + lane * 8,
                       &sB[buf ^ 1][(ntl * 2 + kcl) * 4 + r][0][0]);
        }
        // A fragments direct from global (counted vmcnt, no barrier coupling)
        bf16x8 af[2][4];
        #pragma unroll
        for (int kci = 0; kci < 2; ++kci)
            #pragma unroll
            for (int m = 0; m < 4; ++m)
                af[kci][m] = *(const bf16x8*)(aW + ((size_t)(2 * t + kci) * 4 + m) * 512 + lane * 8);
        #pragma unroll
        for (int kci = 0; kci < 2; ++kci) {
            bf16x8 bfv[4];
            #pragma unroll
            for (int n = 0; n < 4; ++n)
                bfv[n] = *(const bf16x8*)(&sB[buf][(wni * 2 + kci) * 4 + n][lane][0]);
            #pragma unroll
            for (int m = 0; m < 4; ++m)
                #pragma unroll
                for (int n = 0; n < 4; ++n)
                    acc[m][n] = __builtin_amdgcn_mfma_f32_16x16x32_bf16(
                        af[kci][m], bfv[n], acc[m][n], 0, 0, 0);
        }
        __syncthreads();   // drains prefetch; next tile ready
        buf ^= 1;
    }

    // ---- epilogue: bias + stage C tile in LDS, then coalesced row stores ----
    #pragma unroll
    for (int n = 0; n < 4; ++n) {
        const int col = wni * 64 + n * 16 + l16;
        const float bv = bias[nbb * 128 + col];
        #pragma unroll
        for (int m = 0; m < 4; ++m) {
            const int row = wmi * 64 + m * 16 + quad * 4;
            #pragma unroll
            for (int r = 0; r < 4; ++r)
                sC[row + r][col] = (short)f2b(acc[m][n][r] + bv);
        }
    }
    __syncthreads();

    {   // wave covers 32 rows; per inst: quad -> 4 rows, l16 -> full 256B row
        const int m0 = mb * 128, n0 = nbb * 128;
        #pragma unroll
        for (int i = 0; i < 8; ++i) {
            const int row = wave * 32 + i * 4 + quad;
            const int grow = m0 + row;
            if (grow < M) {
                bf16x4 lo = *(const bf16x4*)(&sC[row][l16 * 8]);
                bf16x4 hi = *(const bf16x4*)(&sC[row][l16 * 8 + 4]);
                bf16x8 v;
                v[0]=lo[0]; v[1]=lo[1]; v[2]=lo[2]; v[3]=lo[3];
                v[4]=hi[0]; v[5]=hi[1]; v[6]=hi[2]; v[7]=hi[3];
                *(bf16x8*)(C + (size_t)grow * N + n0 + l16 * 8) = v;
            }
        }
    }
}

// ---------------------------------------------------------------------------
// Projection GEMM (unchanged): fp32 split-K partials. 64x64 tile.
// ---------------------------------------------------------------------------
__global__ __launch_bounds__(256) void gemm_proj_kernel(
    const unsigned short* __restrict__ A1, const unsigned short* __restrict__ W1,
    float* __restrict__ C1,
    const unsigned short* __restrict__ A2, const unsigned short* __restrict__ W2,
    float* __restrict__ C2,
    int zSplit, int M, int N, int ldK, int kLen)
{
    __shared__ short sA[64][72];
    __shared__ short sB[64][72];

    const int z = blockIdx.z;
    const bool s2 = (z >= zSplit);
    const int zi = s2 ? z - zSplit : z;
    const unsigned short* A = s2 ? A2 : A1;
    const unsigned short* W = s2 ? W2 : W1;
    float* C = (s2 ? C2 : C1) + (size_t)zi * M * N;

    const int m0 = blockIdx.x * 64;
    const int n0 = blockIdx.y * 64;
    const int tid = threadIdx.x;
    const int lane = tid & 63;
    const int wave = tid >> 6;
    const int l16 = lane & 15;
    const int quad = lane >> 4;
    const int wr = (wave >> 1) * 32;
    const int wc = (wave & 1) * 32;

    const int lr = tid >> 2;
    const int lc = (tid & 3) * 16;

    f32x4 acc[2][2] = {};

    const int kbase = zi * kLen;
    for (int k0 = kbase; k0 < kbase + kLen; k0 += 64) {
        {
            const int gr = m0 + lr;
            bf16x8 a0 = {}, a1 = {};
            if (gr < M) {
                const unsigned short* ap = A + (size_t)gr * ldK + k0 + lc;
                a0 = ((const bf16x8*)ap)[0];
                a1 = ((const bf16x8*)ap)[1];
            }
            *(bf16x8*)(&sA[lr][lc])     = a0;
            *(bf16x8*)(&sA[lr][lc + 8]) = a1;
            const unsigned short* wp = W + (size_t)(n0 + lr) * ldK + k0 + lc;
            *(bf16x8*)(&sB[lr][lc])     = ((const bf16x8*)wp)[0];
            *(bf16x8*)(&sB[lr][lc + 8]) = ((const bf16x8*)wp)[1];
        }
        __syncthreads();
        #pragma unroll
        for (int ks = 0; ks < 64; ks += 32) {
            bf16x8 a0 = *(const bf16x8*)(&sA[wr + l16][ks + quad * 8]);
            bf16x8 a1 = *(const bf16x8*)(&sA[wr + 16 + l16][ks + quad * 8]);
            bf16x8 b0 = *(const bf16x8*)(&sB[wc + l16][ks + quad * 8]);
            bf16x8 b1 = *(const bf16x8*)(&sB[wc + 16 + l16][ks + quad * 8]);
            acc[0][0] = __builtin_amdgcn_mfma_f32_16x16x32_bf16(a0, b0, acc[0][0], 0, 0, 0);
            acc[0][1] = __builtin_amdgcn_mfma_f32_16x16x32_bf16(a0, b1, acc[0][1], 0, 0, 0);
            acc[1][0] = __builtin_amdgcn_mfma_f32_16x16x32_bf16(a1, b0, acc[1][0], 0, 0, 0);
            acc[1][1] = __builtin_amdgcn_mfma_f32_16x16x32_bf16(a1, b1, acc[1][1], 0, 0, 0);
        }
        __syncthreads();
    }

    #pragma unroll
    for (int s = 0; s < 2; ++s) {
        #pragma unroll
        for (int u = 0; u < 2; ++u) {
            const int col = n0 + wc + u * 16 + l16;
            #pragma unroll
            for (int r = 0; r < 4; ++r) {
                const int row = m0 + wr + s * 16 + quad * 4 + r;
                if (row < M)
                    C[(size_t)row * N + col] = acc[s][u][r];
            }
        }
    }
}

// ===========================================================================
// Phase-2 device helpers (unchanged).
// ===========================================================================
__device__ __forceinline__ void p2_stage_feats(
    const float* fp, short (*fB)[72], int tid)
{
    const float* p = fp + tid * 8;
    float4 x0 = ((const float4*)p)[0];
    float4 x1 = ((const float4*)p)[1];
    bf16x8 v;
    v[0]=(short)f2b(x0.x); v[1]=(short)f2b(x0.y); v[2]=(short)f2b(x0.z); v[3]=(short)f2b(x0.w);
    v[4]=(short)f2b(x1.x); v[5]=(short)f2b(x1.y); v[6]=(short)f2b(x1.z); v[7]=(short)f2b(x1.w);
    *(bf16x8*)(&fB[tid >> 3][(tid & 7) * 8]) = v;
}

__device__ __forceinline__ void p2_stage_64x64(
    const unsigned short* mp, short (*T)[72], int tid)
{
    const unsigned short* p = mp + tid * 16;
    bf16x8 v0 = ((const bf16x8*)p)[0];
    bf16x8 v1 = ((const bf16x8*)p)[1];
    const int d = tid >> 2, c0 = (tid & 3) * 16;
    *(bf16x8*)(&T[d][c0])     = v0;
    *(bf16x8*)(&T[d][c0 + 8]) = v1;
}

__device__ __forceinline__ void p2_stage_32x32(
    const unsigned short* sp, short (*T)[40], int tid)
{
    *(bf16x4*)(&T[tid >> 3][(tid & 7) * 4]) = *(const bf16x4*)(sp + tid * 4);
}

__device__ __forceinline__ void p2_reg_body(
    short (*fB)[72], short (*Mt)[72], short (*sS)[40], short (*X1T)[40],
    float* sRed, unsigned short* outp, int tid)
{
    const int wave = tid >> 6, lane = tid & 63;
    const int l16 = lane & 15, quad = lane >> 4;

    f32x4 accA[2] = {};
    #pragma unroll
    for (int ks = 0; ks < 64; ks += 32) {
        bf16x8 b = *(const bf16x8*)(&Mt[wave * 16 + l16][ks + quad * 8]);
        #pragma unroll
        for (int mt = 0; mt < 2; ++mt) {
            bf16x8 a = *(const bf16x8*)(&fB[mt * 16 + l16][ks + quad * 8]);
            accA[mt] = __builtin_amdgcn_mfma_f32_16x16x32_bf16(a, b, accA[mt], 0, 0, 0);
        }
    }
    float ls = 0.f, lq = 0.f;
    #pragma unroll
    for (int mt = 0; mt < 2; ++mt)
        #pragma unroll
        for (int r = 0; r < 4; ++r) { float v = accA[mt][r]; ls += v; lq += v * v; }
    float mean, istd;
    block_stats(ls, lq, sRed, tid, 1.0f / 2048.0f, mean, istd);
    #pragma unroll
    for (int mt = 0; mt < 2; ++mt) {
        bf16x4 pk;
        #pragma unroll
        for (int r = 0; r < 4; ++r) {
            float y = (accA[mt][r] - mean) * istd;
            pk[r] = (short)f2b(y > 0.f ? y : 0.f);
        }
        *(bf16x4*)(&X1T[wave * 16 + l16][mt * 16 + quad * 4]) = pk;
    }
    __syncthreads();

    f32x4 accB[2] = {};
    {
        bf16x8 b = *(const bf16x8*)(&X1T[wave * 16 + l16][quad * 8]);
        #pragma unroll
        for (int mt = 0; mt < 2; ++mt) {
            bf16x8 a = *(const bf16x8*)(&sS[mt * 16 + l16][quad * 8]);
            accB[mt] = __builtin_amdgcn_mfma_f32_16x16x32_bf16(a, b, accB[mt], 0, 0, 0);
        }
    }
    ls = 0.f; lq = 0.f;
    #pragma unroll
    for (int mt = 0; mt < 2; ++mt)
        #pragma unroll
        for (int r = 0; r < 4; ++r) { float v = accB[mt][r]; ls += v; lq += v * v; }
    block_stats(ls, lq, sRed, tid, 1.0f / 2048.0f, mean, istd);

    const int d = wave * 16 + l16;
    #pragma unroll
    for (int mt = 0; mt < 2; ++mt)
        #pragma unroll
        for (int r = 0; r < 4; ++r) {
            float y = (accB[mt][r] - mean) * istd;
            outp[(mt * 16 + quad * 4 + r) * 64 + d] = f2b(y > 0.f ? y : 0.f);
        }
}

__device__ __forceinline__ void p2_cls_body(
    short (*fB)[72], short (*Vt)[72], short (*kw)[72], short (*vRM)[72],
    short (*vT)[40], short (*kT)[40], short (*sQ)[40], short (*sSC)[40],
    float* sKB, float* sRed, unsigned short* outp, int tid)
{
    const int wave = tid >> 6, lane = tid & 63;
    const int l16 = lane & 15, quad = lane >> 4;

    f32x4 accA[2] = {};
    #pragma unroll
    for (int ks = 0; ks < 64; ks += 32) {
        bf16x8 b = *(const bf16x8*)(&Vt[wave * 16 + l16][ks + quad * 8]);
        #pragma unroll
        for (int mt = 0; mt < 2; ++mt) {
            bf16x8 a = *(const bf16x8*)(&fB[mt * 16 + l16][ks + quad * 8]);
            accA[mt] = __builtin_amdgcn_mfma_f32_16x16x32_bf16(a, b, accA[mt], 0, 0, 0);
        }
    }
    float ls = 0.f, lq = 0.f;
    #pragma unroll
    for (int mt = 0; mt < 2; ++mt)
        #pragma unroll
        for (int r = 0; r < 4; ++r) { float v = accA[mt][r]; ls += v; lq += v * v; }
    float mean, istd;
    block_stats(ls, lq, sRed, tid, 1.0f / 2048.0f, mean, istd);
    {
        const int d = wave * 16 + l16;
        #pragma unroll
        for (int mt = 0; mt < 2; ++mt) {
            bf16x4 pk;
            #pragma unroll
            for (int r = 0; r < 4; ++r) {
                float y = (accA[mt][r] - mean) * istd;
                unsigned short u = f2b(y > 0.f ? y : 0.f);
                pk[r] = (short)u;
                vRM[mt * 16 + quad * 4 + r][d] = (short)u;
            }
            *(bf16x4*)(&vT[d][mt * 16 + quad * 4]) = pk;
        }
    }
    __syncthreads();

    {   // k[i][p] = kw[i]·v[p] + kb
        const int it = wave >> 1, pt = wave & 1;
        f32x4 accK = {};
        #pragma unroll
        for (int ks = 0; ks < 64; ks += 32) {
            bf16x8 a = *(const bf16x8*)(&kw[it * 16 + l16][ks + quad * 8]);
            bf16x8 b = *(const bf16x8*)(&vRM[pt * 16 + l16][ks + quad * 8]);
            accK = __builtin_amdgcn_mfma_f32_16x16x32_bf16(a, b, accK, 0, 0, 0);
        }
        bf16x4 pk;
        #pragma unroll
        for (int r = 0; r < 4; ++r)
            pk[r] = (short)f2b(accK[r] + sKB[it * 16 + quad * 4 + r]);
        *(bf16x4*)(&kT[pt * 16 + l16][it * 16 + quad * 4]) = pk;
    }
    __syncthreads();

    if (wave < 2) {   // logits + softmax
        f32x4 accL[2] = {};
        bf16x8 a = *(const bf16x8*)(&sQ[wave * 16 + l16][quad * 8]);
        #pragma unroll
        for (int pt = 0; pt < 2; ++pt) {
            bf16x8 b = *(const bf16x8*)(&kT[pt * 16 + l16][quad * 8]);
            accL[pt] = __builtin_amdgcn_mfma_f32_16x16x32_bf16(a, b, accL[pt], 0, 0, 0);
        }
        #pragma unroll
        for (int r = 0; r < 4; ++r) {
            float a0 = accL[0][r] * 0.125f, a1 = accL[1][r] * 0.125f;
            float mx = fmaxf(a0, a1);
            #pragma unroll
            for (int m = 1; m < 16; m <<= 1) mx = fmaxf(mx, __shfl_xor(mx, m, 64));
            a0 = __expf(a0 - mx); a1 = __expf(a1 - mx);
            float sum = a0 + a1;
            #pragma unroll
            for (int m = 1; m < 16; m <<= 1) sum += __shfl_xor(sum, m, 64);
            const float inv_s = 1.0f / sum;
            const int o = wave * 16 + quad * 4 + r;
            sSC[o][l16]      = (short)f2b(a0 * inv_s);
            sSC[o][16 + l16] = (short)f2b(a1 * inv_s);
        }
    }
    __syncthreads();

    f32x4 accB[2] = {};
    {
        bf16x8 b = *(const bf16x8*)(&vT[wave * 16 + l16][quad * 8]);
        #pragma unroll
        for (int mt = 0; mt < 2; ++mt) {
            bf16x8 a = *(const bf16x8*)(&sSC[mt * 16 + l16][quad * 8]);
            accB[mt] = __builtin_amdgcn_mfma_f32_16x16x32_bf16(a, b, accB[mt], 0, 0, 0);
        }
    }
    ls = 0.f; lq = 0.f;
    #pragma unroll
    for (int mt = 0; mt < 2; ++mt)
        #pragma unroll
        for (int r = 0; r < 4; ++r) { float v = accB[mt][r]; ls += v; lq += v * v; }
    block_stats(ls, lq, sRed, tid, 1.0f / 2048.0f, mean, istd);

    const int d = wave * 16 + l16;
    #pragma unroll
    for (int mt = 0; mt < 2; ++mt)
        #pragma unroll
        for (int r = 0; r < 4; ++r) {
            float y = (accB[mt][r] - mean) * istd;
            outp[(mt * 16 + quad * 4 + r) * 64 + d] = f2b(y > 0.f ? y : 0.f);
        }
}

__device__ __forceinline__ void p2_stage_cls(
    const unsigned short* Y2row, const float* kwp, const float* kbp, int g,
    short (*kw)[72], short (*sQ)[40], float* sKB, int tid)
{
    {
        const float* kp = kwp + (size_t)g * 2048 + tid * 8;
        float4 x0 = ((const float4*)kp)[0];
        float4 x1 = ((const float4*)kp)[1];
        bf16x8 v;
        v[0]=(short)f2b(x0.x); v[1]=(short)f2b(x0.y); v[2]=(short)f2b(x0.z); v[3]=(short)f2b(x0.w);
        v[4]=(short)f2b(x1.x); v[5]=(short)f2b(x1.y); v[6]=(short)f2b(x1.z); v[7]=(short)f2b(x1.w);
        *(bf16x8*)(&kw[tid >> 3][(tid & 7) * 8]) = v;
    }
    p2_stage_32x32(Y2row + 16384 + g * 1024, sQ, tid);
    if (tid < 32) sKB[tid] = kbp[g * 32 + tid];
}

// ---------------------------------------------------------------------------
// p2 split kernels (small-ws path)
// ---------------------------------------------------------------------------
__global__ __launch_bounds__(256) void p2_reg_kernel(
    const float* __restrict__ feats, const unsigned short* __restrict__ Y1,
    unsigned short* __restrict__ FMS)
{
    const int t = blockIdx.x, g = blockIdx.y;
    const int tid = threadIdx.x;
    __shared__ short fB[32][72];
    __shared__ short Mt[64][72];
    __shared__ short sS[32][40];
    __shared__ short X1T[64][40];
    __shared__ float sRed[16];

    p2_stage_feats(feats + (size_t)(t * NG + g) * 2048, fB, tid);
    p2_stage_64x64(Y1 + (size_t)t * 20480 + g * 4096, Mt, tid);
    p2_stage_32x32(Y1 + (size_t)t * 20480 + 16384 + g * 1024, sS, tid);
    __syncthreads();
    p2_reg_body(fB, Mt, sS, X1T, sRed, FMS + (size_t)t * 8192 + g * 2048, tid);
}

__global__ __launch_bounds__(256) void p2_cls_kernel(
    const float* __restrict__ feats, const unsigned short* __restrict__ Y2,
    const float* __restrict__ kwp, const float* __restrict__ kbp,
    unsigned short* __restrict__ FC)
{
    const int t = blockIdx.x, g = blockIdx.y;
    const int tid = threadIdx.x;
    __shared__ short fB[32][72];
    __shared__ short Vt[64][72];
    __shared__ short kw[32][72];
    __shared__ short vRM[32][72];
    __shared__ short vT[64][40];
    __shared__ short kT[32][40];
    __shared__ short sQ[32][40];
    __shared__ short sSC[32][40];
    __shared__ float sKB[32];
    __shared__ float sRed[16];

    p2_stage_feats(feats + (size_t)(t * NG + g) * 2048, fB, tid);
    p2_stage_64x64(Y2 + (size_t)t * 20480 + g * 4096, Vt, tid);
    p2_stage_cls(Y2 + (size_t)t * 20480, kwp, kbp, g, kw, sQ, sKB, tid);
    __syncthreads();
    p2_cls_body(fB, Vt, kw, vRM, vT, kT, sQ, sSC, sKB, sRed,
                FC + (size_t)t * 8192 + g * 2048, tid);
}

// ---------------------------------------------------------------------------
// p2 fused kernel (big-ws path)
// ---------------------------------------------------------------------------
__global__ __launch_bounds__(256) void p2_fused_kernel(
    const float* __restrict__ feats,
    const unsigned short* __restrict__ Y1,
    const unsigned short* __restrict__ Y2,
    const float* __restrict__ kwp, const float* __restrict__ kbp,
    unsigned short* __restrict__ FMS, unsigned short* __restrict__ FC)
{
    const int t = blockIdx.x, g = blockIdx.y;
    const int tid = threadIdx.x;
    __shared__ short fB[32][72];
    __shared__ short MtVt[64][72];
    __shared__ short XvT[64][40];
    __shared__ short sSQ[32][40];
    __shared__ short kw[32][72];
    __shared__ short vRM[32][72];
    __shared__ short kT[32][40];
    __shared__ short sSC[32][40];
    __shared__ float sKB[32];
    __shared__ float sRed[16];

    p2_stage_feats(feats + (size_t)(t * NG + g) * 2048, fB, tid);
    p2_stage_64x64(Y1 + (size_t)t * 20480 + g * 4096, MtVt, tid);
    p2_stage_32x32(Y1 + (size_t)t * 20480 + 16384 + g * 1024, sSQ, tid);
    __syncthreads();
    p2_reg_body(fB, MtVt, sSQ, XvT, sRed, FMS + (size_t)t * 8192 + g * 2048, tid);
    __syncthreads();
    p2_stage_64x64(Y2 + (size_t)t * 20480 + g * 4096, MtVt, tid);
    p2_stage_cls(Y2 + (size_t)t * 20480, kwp, kbp, g, kw, sSQ, sKB, tid);
    __syncthreads();
    p2_cls_body(fB, MtVt, kw, vRM, XvT, kT, sSQ, sSC, sKB, sRed,
                FC + (size_t)t * 8192 + g * 2048, tid);
}

// ---------------------------------------------------------------------------
// Final: reduce split-K=8 partials, residual add, affine LN over 256, fp32 out.
// ---------------------------------------------------------------------------
__global__ __launch_bounds__(256) void final_ln_kernel(
    const float* __restrict__ qv,
    const float* __restrict__ MSP, const float* __restrict__ CLP,
    const float* __restrict__ Wv_b, const float* __restrict__ Wv2_b,
    const float* __restrict__ lnA_w, const float* __restrict__ lnA_b,
    const float* __restrict__ lnB_w, const float* __restrict__ lnB_b,
    float* __restrict__ out)
{
    __shared__ float sRed[16];
    const int t = blockIdx.x;
    const int br = blockIdx.y;
    const int c = threadIdx.x;
    const float* P = br ? CLP : MSP;
    const float* bias = br ? Wv2_b : Wv_b;
    const float* lw = br ? lnB_w : lnA_w;
    const float* lb = br ? lnB_b : lnA_b;

    float x = qv[t * 256 + c] + bias[c];
    #pragma unroll
    for (int s = 0; s < 8; ++s) x += P[(size_t)s * (BN * 256) + t * 256 + c];

    float mean, istd;
    block_stats(x, x * x, sRed, c, 1.0f / 256.0f, mean, istd);
    out[(size_t)br * (BN * 256) + t * 256 + c] = (x - mean) * istd * lw[c] + lb[c];
}

// ---------------------------------------------------------------------------
extern "C" void kernel_launch(void* const* d_in, const int* in_sizes, int n_in,
                              void* d_out, int out_size, void* d_ws, size_t ws_size,
                              hipStream_t stream) {
    const float* feats = (const float*)d_in[0];
    const float* qv    = (const float*)d_in[1];
    const float* m_w   = (const float*)d_in[7];
    const float* m_b   = (const float*)d_in[8];
    const float* s_w   = (const float*)d_in[9];
    const float* s_b   = (const float*)d_in[10];
    const float* q_w   = (const float*)d_in[11];
    const float* q_b   = (const float*)d_in[12];
    const float* v_w   = (const float*)d_in[13];
    const float* v_b   = (const float*)d_in[14];
    const float* k_w   = (const float*)d_in[15];
    const float* k_b   = (const float*)d_in[16];
    const float* Wv_w  = (const float*)d_in[17];
    const float* Wv_b  = (const float*)d_in[18];
    const float* Wv2_w = (const float*)d_in[19];
    const float* Wv2_b = (const float*)d_in[20];
    const float* lnA_w = (const float*)d_in[21];
    const float* lnA_b = (const float*)d_in[22];
    const float* lnB_w = (const float*)d_in[23];
    const float* lnB_b = (const float*)d_in[24];

    char* ws = (char*)d_ws;
    const dim3 blk(256);

    if (ws_size >= 275251200ull) {
        // ===== BIG path (275.3 MB) =====
        unsigned short* Y1 = (unsigned short*)(ws);
        unsigned short* Y2 = (unsigned short*)(ws + 98304000);
        unsigned short* W1   = (unsigned short*)(ws + 196608000);
        unsigned short* W2   = (unsigned short*)(ws + 196608000 + 10485760);
        unsigned short* qvP  = (unsigned short*)(ws + 196608000 + 20971520);  // 1,245,184 B
        float* b1 = (float*)(ws + 196608000 + 22216704);
        float* b2 = (float*)(ws + 196608000 + 22298624);
        unsigned short* FMS = (unsigned short*)(ws + 196608000);
        unsigned short* FC  = (unsigned short*)(ws + 235929600);
        unsigned short* WvB  = (unsigned short*)(ws + 98304000);
        unsigned short* Wv2B = (unsigned short*)(ws + 98304000 + 4194304);
        float* MSP = (float*)(ws);
        float* CLP = (float*)(ws + 19660800);

        prep_perm_kernel<<<dim3(4096, 2), blk, 0, stream>>>(m_w, m_b, W1, b1,
                                                            v_w, v_b, W2, b2);
        prep_flat_frag_kernel<<<dim3(512, 2), blk, 0, stream>>>(s_w, W1, q_w, W2);
        prep_pack_a_kernel<<<304, blk, 0, stream>>>(qv, qvP);
        copy_bias_kernel<<<dim3(16, 2), blk, 0, stream>>>(s_b, b1 + 16384, q_b, b2 + 16384);
        gemm_gen_kernel<<<dim3(19, 320), blk, 0, stream>>>(
            qvP, W1, b1, Y1, W2, b2, Y2, 160, BN, 20480);
        p2_fused_kernel<<<dim3(BN, NG), blk, 0, stream>>>(
            feats, Y1, Y2, k_w, k_b, FMS, FC);
        prep_flat_kernel<<<dim3(1024, 2), blk, 0, stream>>>(
            Wv_w, WvB, 256 * 8192, Wv2_w, Wv2B, 256 * 8192, nullptr, nullptr, 0);
        gemm_proj_kernel<<<dim3(38, 4, 16), blk, 0, stream>>>(
            FMS, WvB, MSP, FC, Wv2B, CLP, 8, BN, 256, 8192, 1024);
        final_ln_kernel<<<dim3(BN, 2), blk, 0, stream>>>(
            qv, MSP, CLP, Wv_b, Wv2_b, lnA_w, lnA_b, lnB_w, lnB_b, (float*)d_out);
    } else {
        // ===== SMALL path (176.9 MB fallback) =====
        unsigned short* Y1  = (unsigned short*)(ws);
        unsigned short* FMS = (unsigned short*)(ws + 98304000);
        unsigned short* FC  = (unsigned short*)(ws + 137625600);
        unsigned short* W1   = (unsigned short*)(ws + 137625600);
        unsigned short* W2   = (unsigned short*)(ws + 137625600 + 10485760);
        unsigned short* qvP  = (unsigned short*)(ws + 137625600 + 20971520);
        float* b1 = (float*)(ws + 137625600 + 22216704);
        float* b2 = (float*)(ws + 137625600 + 22298624);
        float* MSP = (float*)(ws);
        float* CLP = (float*)(ws + 19660800);
        unsigned short* WvB  = (unsigned short*)(ws + 39321600);
        unsigned short* Wv2B = (unsigned short*)(ws + 43515904);

        prep_perm_kernel<<<dim3(4096, 2), blk, 0, stream>>>(m_w, m_b, W1, b1,
                                                            v_w, v_b, W2, b2);
        prep_flat_frag_kernel<<<dim3(512, 2), blk, 0, stream>>>(s_w, W1, q_w, W2);
        prep_pack_a_kernel<<<304, blk, 0, stream>>>(qv, qvP);
        copy_bias_kernel<<<dim3(16, 2), blk, 0, stream>>>(s_b, b1 + 16384, q_b, b2 + 16384);
        gemm_gen_kernel<<<dim3(19, 160), blk, 0, stream>>>(
            qvP, W1, b1, Y1, W1, b1, Y1, 160, BN, 20480);
        p2_reg_kernel<<<dim3(BN, NG), blk, 0, stream>>>(feats, Y1, FMS);
        gemm_gen_kernel<<<dim3(19, 160), blk, 0, stream>>>(
            qvP, W2, b2, Y1, W2, b2, Y1, 160, BN, 20480);
        p2_cls_kernel<<<dim3(BN, NG), blk, 0, stream>>>(feats, Y1, k_w, k_b, FC);
        prep_flat_kernel<<<dim3(1024, 2), blk, 0, stream>>>(
            Wv_w, WvB, 256 * 8192, Wv2_w, Wv2B, 256 * 8192, nullptr, nullptr, 0);
        gemm_proj_kernel<<<dim3(38, 4, 8), blk, 0, stream>>>(
            FMS, WvB, MSP, FMS, WvB, MSP, 8, BN, 256, 8192, 1024);
        gemm_proj_kernel<<<dim3(38, 4, 8), blk, 0, stream>>>(
            FC, Wv2B, CLP, FC, Wv2B, CLP, 8, BN, 256, 8192, 1024);
        final_ln_kernel<<<dim3(BN, 2), blk, 0, stream>>>(
            qv, MSP, CLP, Wv_b, Wv2_b, lnA_w, lnA_b, lnB_w, lnB_b, (float*)d_out);
    }
}

// Round 3
// 407.360 us; speedup vs baseline: 1.1293x; 1.0248x over previous
//
#include <hip/hip_runtime.h>

// Problem constants
#define BN    2400   // B*N
#define NG    4      // groups
#define DIM   256

// R14: p2_fused latency attack (95us, MfmaUtil 3.9%, Occ 39% -> latency-bound).
//  - LDS 36.3KB -> 28.9KB (sSC aliased into vRM; kw staged into fB's space
//    after cls-QK) -> 5 blocks/CU; __launch_bounds__(256,5).
//  - block_stats2: one barrier (leaders write partials; ALL threads
//    redundantly reduce 8 floats from LDS broadcast) vs 2 barriers + serial
//    tid==0 section. x4 calls.
//  - T14 prefetch: all global loads (feats,M,S,V,Q,kw,kb) issued at kernel
//    entry into registers; mid-kernel staging is pure ds_write, removing the
//    second exposed global-latency bubble + one structural barrier.
// gemm_gen / gemm_proj / preps / final unchanged from R13.

typedef __attribute__((ext_vector_type(8))) short bf16x8;
typedef __attribute__((ext_vector_type(4))) short bf16x4;
typedef __attribute__((ext_vector_type(4))) float f32x4;

__device__ __forceinline__ float b2f(unsigned short u) {
    union { unsigned int i; float f; } v; v.i = ((unsigned int)u) << 16; return v.f;
}
__device__ __forceinline__ unsigned short f2b(float f) {
    union { float f; unsigned int i; } v; v.f = f;
    unsigned int x = v.i;
    return (unsigned short)((x + 0x7fffu + ((x >> 16) & 1u)) >> 16);  // RNE
}

__device__ __forceinline__ void glds16(const unsigned short* g, const short* l) {
    __builtin_amdgcn_global_load_lds(
        (const __attribute__((address_space(1))) unsigned int*)(const void*)g,
        (__attribute__((address_space(3))) unsigned int*)(void*)const_cast<short*>(l),
        16, 0, 0);
}

__device__ __forceinline__ void block_stats(float s, float q, float* sRed, int tid,
                                            float inv_n, float& mean, float& istd) {
    #pragma unroll
    for (int off = 32; off > 0; off >>= 1) {
        s += __shfl_down(s, off, 64);
        q += __shfl_down(q, off, 64);
    }
    if ((tid & 63) == 0) { sRed[(tid >> 6) * 2] = s; sRed[(tid >> 6) * 2 + 1] = q; }
    __syncthreads();
    if (tid == 0) {
        float ts = 0.f, tq = 0.f;
        for (int w = 0; w < 4; ++w) { ts += sRed[2 * w]; tq += sRed[2 * w + 1]; }
        float m = ts * inv_n;
        float var = tq * inv_n - m * m;
        sRed[8] = m; sRed[9] = rsqrtf(var + 1e-5f);
    }
    __syncthreads();
    mean = sRed[8]; istd = sRed[9];
}

// single-barrier variant: leaders write partials; every thread reduces the
// 4 partial pairs itself (LDS broadcast reads). Caller guarantees a
// __syncthreads between consecutive calls (true in p2_fused_kernel).
__device__ __forceinline__ void block_stats2(float s, float q, float* sRed, int tid,
                                             float inv_n, float& mean, float& istd) {
    #pragma unroll
    for (int off = 32; off > 0; off >>= 1) {
        s += __shfl_down(s, off, 64);
        q += __shfl_down(q, off, 64);
    }
    if ((tid & 63) == 0) { sRed[(tid >> 6) * 2] = s; sRed[(tid >> 6) * 2 + 1] = q; }
    __syncthreads();
    float ts = 0.f, tq = 0.f;
    #pragma unroll
    for (int w = 0; w < 4; ++w) { ts += sRed[2 * w]; tq += sRed[2 * w + 1]; }
    mean = ts * inv_n;
    float var = tq * inv_n - mean * mean;
    istd = rsqrtf(var + 1e-5f);
}

// ---------------------------------------------------------------------------
// Weight preps. Fragment-major addressing for within-branch out-row n, col k:
//   nt=n>>6, rg=(n>>4)&3, r16=n&15, kc=k>>5, q=(k>>3)&3, j=k&7, lane=r16|(q<<4)
//   elem = (((nt*8+kc)*4+rg)*64+lane)*8 + j
// ---------------------------------------------------------------------------
__global__ __launch_bounds__(256) void prep_perm_kernel(
    const float* __restrict__ wA, const float* __restrict__ bA,
    unsigned short* __restrict__ oA, float* __restrict__ obA,
    const float* __restrict__ wB, const float* __restrict__ bB,
    unsigned short* __restrict__ oB, float* __restrict__ obB)
{
    const float* w = blockIdx.y ? wB : wA;
    const float* b = blockIdx.y ? bB : bA;
    unsigned short* wOut = blockIdx.y ? oB : oA;
    float* bOut = blockIdx.y ? obB : obA;

    const int row_o = blockIdx.x * 4 + (threadIdx.x >> 6);
    const int lane = threadIdx.x & 63;
    const int g = row_o >> 12, d = (row_o >> 6) & 63, c = row_o & 63;
    const int row_i = (g << 12) + c * 64 + d;
    const float4 x = *(const float4*)(w + (size_t)row_i * 256 + lane * 4);
    bf16x4 pk;
    pk[0] = (short)f2b(x.x); pk[1] = (short)f2b(x.y);
    pk[2] = (short)f2b(x.z); pk[3] = (short)f2b(x.w);

    const int k0 = lane * 4;
    const int nt = row_o >> 6, rg = (row_o >> 4) & 3, r16 = row_o & 15;
    const int kc = k0 >> 5, q = (k0 >> 3) & 3, j = k0 & 7;
    const int lp = r16 | (q << 4);
    *(bf16x4*)(wOut + ((((size_t)(nt * 8 + kc) * 4 + rg) * 64 + lp) * 8 + j)) = pk;
    if (lane == 0) bOut[row_o] = b[row_i];
}

// fragment-major pack of s_w / q_w into rows n = 16384 + r of each branch
__global__ __launch_bounds__(256) void prep_flat_frag_kernel(
    const float* __restrict__ a0, unsigned short* __restrict__ o0,
    const float* __restrict__ a1, unsigned short* __restrict__ o1)
{
    const float* src = blockIdx.y ? a1 : a0;
    unsigned short* dst = blockIdx.y ? o1 : o0;
    const int idx = (blockIdx.x * 256 + threadIdx.x) * 8;
    if (idx >= 4096 * 256) return;
    float4 x0 = ((const float4*)(src + idx))[0];
    float4 x1 = ((const float4*)(src + idx))[1];
    bf16x8 v;
    v[0]=(short)f2b(x0.x); v[1]=(short)f2b(x0.y); v[2]=(short)f2b(x0.z); v[3]=(short)f2b(x0.w);
    v[4]=(short)f2b(x1.x); v[5]=(short)f2b(x1.y); v[6]=(short)f2b(x1.z); v[7]=(short)f2b(x1.w);

    const int r = idx >> 8;
    const int k0 = idx & 255;
    const int n = 16384 + r;
    const int nt = n >> 6, rg = (n >> 4) & 3, r16 = n & 15;
    const int kc = k0 >> 5, q = (k0 >> 3) & 3;
    const int lp = r16 | (q << 4);
    *(bf16x8*)(dst + (((size_t)(nt * 8 + kc) * 4 + rg) * 64 + lp) * 8) = v;
}

// flat bf16 cast (kept for projection weights)
__global__ __launch_bounds__(256) void prep_flat_kernel(
    const float* __restrict__ a0, unsigned short* __restrict__ o0, int n0,
    const float* __restrict__ a1, unsigned short* __restrict__ o1, int n1,
    const float* __restrict__ a2, unsigned short* __restrict__ o2, int n2)
{
    const float* src; unsigned short* dst; int n;
    if (blockIdx.y == 0)      { src = a0; dst = o0; n = n0; }
    else if (blockIdx.y == 1) { src = a1; dst = o1; n = n1; }
    else                      { src = a2; dst = o2; n = n2; }
    const int idx = (blockIdx.x * 256 + threadIdx.x) * 8;
    if (idx >= n) return;
    float4 x0 = ((const float4*)(src + idx))[0];
    float4 x1 = ((const float4*)(src + idx))[1];
    bf16x8 v;
    v[0]=(short)f2b(x0.x); v[1]=(short)f2b(x0.y); v[2]=(short)f2b(x0.z); v[3]=(short)f2b(x0.w);
    v[4]=(short)f2b(x1.x); v[5]=(short)f2b(x1.y); v[6]=(short)f2b(x1.z); v[7]=(short)f2b(x1.w);
    *(bf16x8*)(dst + idx) = v;
}

__global__ __launch_bounds__(256) void copy_bias_kernel(
    const float* __restrict__ a0, float* __restrict__ o0,
    const float* __restrict__ a1, float* __restrict__ o1)
{
    const int i = blockIdx.x * 256 + threadIdx.x;
    if (blockIdx.y == 0) o0[i] = a0[i]; else o1[i] = a1[i];
}

// ---------------------------------------------------------------------------
// Pack qv (fp32, BN x 256) into MFMA-A-fragment-major bf16:
// qvP[mt][kc][rg][lane][8] = qv[mt*64 + rg*16 + (lane&15)][kc*32 + (lane>>4)*8 + j]
// ---------------------------------------------------------------------------
__global__ __launch_bounds__(256) void prep_pack_a_kernel(
    const float* __restrict__ qv, unsigned short* __restrict__ qvP)
{
    const int idx = blockIdx.x * 256 + threadIdx.x;   // chunk index
    if (idx >= 38 * 8 * 4 * 64) return;
    const int lane = idx & 63;
    const int rg   = (idx >> 6) & 3;
    const int kc   = (idx >> 8) & 7;
    const int mt   = idx >> 11;
    int row = mt * 64 + rg * 16 + (lane & 15);
    if (row >= BN) row = BN - 1;
    const int col = kc * 32 + (lane >> 4) * 8;
    const float* p = qv + (size_t)row * 256 + col;
    float4 x0 = ((const float4*)p)[0];
    float4 x1 = ((const float4*)p)[1];
    bf16x8 v;
    v[0]=(short)f2b(x0.x); v[1]=(short)f2b(x0.y); v[2]=(short)f2b(x0.z); v[3]=(short)f2b(x0.w);
    v[4]=(short)f2b(x1.x); v[5]=(short)f2b(x1.y); v[6]=(short)f2b(x1.z); v[7]=(short)f2b(x1.w);
    *(bf16x8*)(qvP + (size_t)idx * 8) = v;
}

// ---------------------------------------------------------------------------
// Generator GEMM: C = qv * W^T + bias, bf16 out. 128x128 tile, BK=64,
// 4 waves 2x2 each 64x64 (4x4 fragments).
// A direct from qvP (global, fragment-major); B double-buffered in LDS via
// global_load_lds(16) with prefetch-before-compute; LDS-coalesced epilogue.
// ---------------------------------------------------------------------------
__global__ __launch_bounds__(256) void gemm_gen_kernel(
    const unsigned short* __restrict__ qvP,
    const unsigned short* __restrict__ W1, const float* __restrict__ b1,
    unsigned short* __restrict__ C1,
    const unsigned short* __restrict__ W2, const float* __restrict__ b2,
    unsigned short* __restrict__ C2,
    int ySplit, int M, int N)
{
    // union: main loop 2 x 16KB B buffers; epilogue 128 x 132 bf16 C tile
    __shared__ __align__(16) char smem[33792];
    short (*sB)[16][64][8] = (short (*)[16][64][8])smem;
    short (*sC)[132]       = (short (*)[132])smem;

    // XCD-aware bijective swizzle (nwg % 8 == 0 by construction).
    const int flat = blockIdx.y * gridDim.x + blockIdx.x;
    const int nwg = gridDim.x * gridDim.y;
    const int wg = (flat & 7) * (nwg >> 3) + (flat >> 3);
    const int mb = wg % gridDim.x;      // gridDim.x = 19
    const int nb = wg / gridDim.x;

    const bool s2 = (nb >= ySplit);
    const unsigned short* Wp = s2 ? W2 : W1;
    const float* bias = s2 ? b2 : b1;
    unsigned short* C = s2 ? C2 : C1;
    const int nbb = s2 ? nb - ySplit : nb;

    const int tid = threadIdx.x;
    const int lane = tid & 63;
    const int wave = tid >> 6;
    const int l16 = lane & 15;
    const int quad = lane >> 4;
    const int wmi = wave >> 1;   // wave m half
    const int wni = wave & 1;    // wave n half

    // B staging assignment: wave covers (ntl, kcl), 4 rg chunks of 1KB
    const int ntl = wave >> 1, kcl = wave & 1;
    const unsigned short* bSrc = Wp + (size_t)(nbb * 2 + ntl) * 16384;
    // A direct base for this wave's m-half
    const unsigned short* aW = qvP + (size_t)(mb * 2 + wmi) * 16384;

    f32x4 acc[4][4] = {};

    // prologue: stage B tile t=0 into buf 0
    #pragma unroll
    for (int r = 0; r < 4; ++r)
        glds16(bSrc + ((size_t)(0 + kcl) * 4 + r) * 512 + lane * 8,
               &sB[0][(ntl * 2 + kcl) * 4 + r][0][0]);
    __syncthreads();

    int buf = 0;
    for (int t = 0; t < 4; ++t) {
        // prefetch next B tile BEFORE compute (latency hides under MFMA)
        if (t < 3) {
            #pragma unroll
            for (int r = 0; r < 4; ++r)
                glds16(bSrc + ((size_t)(2 * (t + 1) + kcl) * 4 + r) * 512 + lane * 8,
                       &sB[buf ^ 1][(ntl * 2 + kcl) * 4 + r][0][0]);
        }
        // A fragments direct from global (counted vmcnt, no barrier coupling)
        bf16x8 af[2][4];
        #pragma unroll
        for (int kci = 0; kci < 2; ++kci)
            #pragma unroll
            for (int m = 0; m < 4; ++m)
                af[kci][m] = *(const bf16x8*)(aW + ((size_t)(2 * t + kci) * 4 + m) * 512 + lane * 8);
        #pragma unroll
        for (int kci = 0; kci < 2; ++kci) {
            bf16x8 bfv[4];
            #pragma unroll
            for (int n = 0; n < 4; ++n)
                bfv[n] = *(const bf16x8*)(&sB[buf][(wni * 2 + kci) * 4 + n][lane][0]);
            #pragma unroll
            for (int m = 0; m < 4; ++m)
                #pragma unroll
                for (int n = 0; n < 4; ++n)
                    acc[m][n] = __builtin_amdgcn_mfma_f32_16x16x32_bf16(
                        af[kci][m], bfv[n], acc[m][n], 0, 0, 0);
        }
        __syncthreads();   // drains prefetch; next tile ready
        buf ^= 1;
    }

    // ---- epilogue: bias + stage C tile in LDS, then coalesced row stores ----
    #pragma unroll
    for (int n = 0; n < 4; ++n) {
        const int col = wni * 64 + n * 16 + l16;
        const float bv = bias[nbb * 128 + col];
        #pragma unroll
        for (int m = 0; m < 4; ++m) {
            const int row = wmi * 64 + m * 16 + quad * 4;
            #pragma unroll
            for (int r = 0; r < 4; ++r)
                sC[row + r][col] = (short)f2b(acc[m][n][r] + bv);
        }
    }
    __syncthreads();

    {   // wave covers 32 rows; per inst: quad -> 4 rows, l16 -> full 256B row
        const int m0 = mb * 128, n0 = nbb * 128;
        #pragma unroll
        for (int i = 0; i < 8; ++i) {
            const int row = wave * 32 + i * 4 + quad;
            const int grow = m0 + row;
            if (grow < M) {
                bf16x4 lo = *(const bf16x4*)(&sC[row][l16 * 8]);
                bf16x4 hi = *(const bf16x4*)(&sC[row][l16 * 8 + 4]);
                bf16x8 v;
                v[0]=lo[0]; v[1]=lo[1]; v[2]=lo[2]; v[3]=lo[3];
                v[4]=hi[0]; v[5]=hi[1]; v[6]=hi[2]; v[7]=hi[3];
                *(bf16x8*)(C + (size_t)grow * N + n0 + l16 * 8) = v;
            }
        }
    }
}

// ---------------------------------------------------------------------------
// Projection GEMM (unchanged): fp32 split-K partials. 64x64 tile.
// ---------------------------------------------------------------------------
__global__ __launch_bounds__(256) void gemm_proj_kernel(
    const unsigned short* __restrict__ A1, const unsigned short* __restrict__ W1,
    float* __restrict__ C1,
    const unsigned short* __restrict__ A2, const unsigned short* __restrict__ W2,
    float* __restrict__ C2,
    int zSplit, int M, int N, int ldK, int kLen)
{
    __shared__ short sA[64][72];
    __shared__ short sB[64][72];

    const int z = blockIdx.z;
    const bool s2 = (z >= zSplit);
    const int zi = s2 ? z - zSplit : z;
    const unsigned short* A = s2 ? A2 : A1;
    const unsigned short* W = s2 ? W2 : W1;
    float* C = (s2 ? C2 : C1) + (size_t)zi * M * N;

    const int m0 = blockIdx.x * 64;
    const int n0 = blockIdx.y * 64;
    const int tid = threadIdx.x;
    const int lane = tid & 63;
    const int wave = tid >> 6;
    const int l16 = lane & 15;
    const int quad = lane >> 4;
    const int wr = (wave >> 1) * 32;
    const int wc = (wave & 1) * 32;

    const int lr = tid >> 2;
    const int lc = (tid & 3) * 16;

    f32x4 acc[2][2] = {};

    const int kbase = zi * kLen;
    for (int k0 = kbase; k0 < kbase + kLen; k0 += 64) {
        {
            const int gr = m0 + lr;
            bf16x8 a0 = {}, a1 = {};
            if (gr < M) {
                const unsigned short* ap = A + (size_t)gr * ldK + k0 + lc;
                a0 = ((const bf16x8*)ap)[0];
                a1 = ((const bf16x8*)ap)[1];
            }
            *(bf16x8*)(&sA[lr][lc])     = a0;
            *(bf16x8*)(&sA[lr][lc + 8]) = a1;
            const unsigned short* wp = W + (size_t)(n0 + lr) * ldK + k0 + lc;
            *(bf16x8*)(&sB[lr][lc])     = ((const bf16x8*)wp)[0];
            *(bf16x8*)(&sB[lr][lc + 8]) = ((const bf16x8*)wp)[1];
        }
        __syncthreads();
        #pragma unroll
        for (int ks = 0; ks < 64; ks += 32) {
            bf16x8 a0 = *(const bf16x8*)(&sA[wr + l16][ks + quad * 8]);
            bf16x8 a1 = *(const bf16x8*)(&sA[wr + 16 + l16][ks + quad * 8]);
            bf16x8 b0 = *(const bf16x8*)(&sB[wc + l16][ks + quad * 8]);
            bf16x8 b1 = *(const bf16x8*)(&sB[wc + 16 + l16][ks + quad * 8]);
            acc[0][0] = __builtin_amdgcn_mfma_f32_16x16x32_bf16(a0, b0, acc[0][0], 0, 0, 0);
            acc[0][1] = __builtin_amdgcn_mfma_f32_16x16x32_bf16(a0, b1, acc[0][1], 0, 0, 0);
            acc[1][0] = __builtin_amdgcn_mfma_f32_16x16x32_bf16(a1, b0, acc[1][0], 0, 0, 0);
            acc[1][1] = __builtin_amdgcn_mfma_f32_16x16x32_bf16(a1, b1, acc[1][1], 0, 0, 0);
        }
        __syncthreads();
    }

    #pragma unroll
    for (int s = 0; s < 2; ++s) {
        #pragma unroll
        for (int u = 0; u < 2; ++u) {
            const int col = n0 + wc + u * 16 + l16;
            #pragma unroll
            for (int r = 0; r < 4; ++r) {
                const int row = m0 + wr + s * 16 + quad * 4 + r;
                if (row < M)
                    C[(size_t)row * N + col] = acc[s][u][r];
            }
        }
    }
}

// ===========================================================================
// Phase-2 device helpers (used by small-ws split kernels; unchanged).
// ===========================================================================
__device__ __forceinline__ void p2_stage_feats(
    const float* fp, short (*fB)[72], int tid)
{
    const float* p = fp + tid * 8;
    float4 x0 = ((const float4*)p)[0];
    float4 x1 = ((const float4*)p)[1];
    bf16x8 v;
    v[0]=(short)f2b(x0.x); v[1]=(short)f2b(x0.y); v[2]=(short)f2b(x0.z); v[3]=(short)f2b(x0.w);
    v[4]=(short)f2b(x1.x); v[5]=(short)f2b(x1.y); v[6]=(short)f2b(x1.z); v[7]=(short)f2b(x1.w);
    *(bf16x8*)(&fB[tid >> 3][(tid & 7) * 8]) = v;
}

__device__ __forceinline__ void p2_stage_64x64(
    const unsigned short* mp, short (*T)[72], int tid)
{
    const unsigned short* p = mp + tid * 16;
    bf16x8 v0 = ((const bf16x8*)p)[0];
    bf16x8 v1 = ((const bf16x8*)p)[1];
    const int d = tid >> 2, c0 = (tid & 3) * 16;
    *(bf16x8*)(&T[d][c0])     = v0;
    *(bf16x8*)(&T[d][c0 + 8]) = v1;
}

__device__ __forceinline__ void p2_stage_32x32(
    const unsigned short* sp, short (*T)[40], int tid)
{
    *(bf16x4*)(&T[tid >> 3][(tid & 7) * 4]) = *(const bf16x4*)(sp + tid * 4);
}

__device__ __forceinline__ void p2_reg_body(
    short (*fB)[72], short (*Mt)[72], short (*sS)[40], short (*X1T)[40],
    float* sRed, unsigned short* outp, int tid)
{
    const int wave = tid >> 6, lane = tid & 63;
    const int l16 = lane & 15, quad = lane >> 4;

    f32x4 accA[2] = {};
    #pragma unroll
    for (int ks = 0; ks < 64; ks += 32) {
        bf16x8 b = *(const bf16x8*)(&Mt[wave * 16 + l16][ks + quad * 8]);
        #pragma unroll
        for (int mt = 0; mt < 2; ++mt) {
            bf16x8 a = *(const bf16x8*)(&fB[mt * 16 + l16][ks + quad * 8]);
            accA[mt] = __builtin_amdgcn_mfma_f32_16x16x32_bf16(a, b, accA[mt], 0, 0, 0);
        }
    }
    float ls = 0.f, lq = 0.f;
    #pragma unroll
    for (int mt = 0; mt < 2; ++mt)
        #pragma unroll
        for (int r = 0; r < 4; ++r) { float v = accA[mt][r]; ls += v; lq += v * v; }
    float mean, istd;
    block_stats(ls, lq, sRed, tid, 1.0f / 2048.0f, mean, istd);
    #pragma unroll
    for (int mt = 0; mt < 2; ++mt) {
        bf16x4 pk;
        #pragma unroll
        for (int r = 0; r < 4; ++r) {
            float y = (accA[mt][r] - mean) * istd;
            pk[r] = (short)f2b(y > 0.f ? y : 0.f);
        }
        *(bf16x4*)(&X1T[wave * 16 + l16][mt * 16 + quad * 4]) = pk;
    }
    __syncthreads();

    f32x4 accB[2] = {};
    {
        bf16x8 b = *(const bf16x8*)(&X1T[wave * 16 + l16][quad * 8]);
        #pragma unroll
        for (int mt = 0; mt < 2; ++mt) {
            bf16x8 a = *(const bf16x8*)(&sS[mt * 16 + l16][quad * 8]);
            accB[mt] = __builtin_amdgcn_mfma_f32_16x16x32_bf16(a, b, accB[mt], 0, 0, 0);
        }
    }
    ls = 0.f; lq = 0.f;
    #pragma unroll
    for (int mt = 0; mt < 2; ++mt)
        #pragma unroll
        for (int r = 0; r < 4; ++r) { float v = accB[mt][r]; ls += v; lq += v * v; }
    block_stats(ls, lq, sRed, tid, 1.0f / 2048.0f, mean, istd);

    const int d = wave * 16 + l16;
    #pragma unroll
    for (int mt = 0; mt < 2; ++mt)
        #pragma unroll
        for (int r = 0; r < 4; ++r) {
            float y = (accB[mt][r] - mean) * istd;
            outp[(mt * 16 + quad * 4 + r) * 64 + d] = f2b(y > 0.f ? y : 0.f);
        }
}

__device__ __forceinline__ void p2_cls_body(
    short (*fB)[72], short (*Vt)[72], short (*kw)[72], short (*vRM)[72],
    short (*vT)[40], short (*kT)[40], short (*sQ)[40], short (*sSC)[40],
    float* sKB, float* sRed, unsigned short* outp, int tid)
{
    const int wave = tid >> 6, lane = tid & 63;
    const int l16 = lane & 15, quad = lane >> 4;

    f32x4 accA[2] = {};
    #pragma unroll
    for (int ks = 0; ks < 64; ks += 32) {
        bf16x8 b = *(const bf16x8*)(&Vt[wave * 16 + l16][ks + quad * 8]);
        #pragma unroll
        for (int mt = 0; mt < 2; ++mt) {
            bf16x8 a = *(const bf16x8*)(&fB[mt * 16 + l16][ks + quad * 8]);
            accA[mt] = __builtin_amdgcn_mfma_f32_16x16x32_bf16(a, b, accA[mt], 0, 0, 0);
        }
    }
    float ls = 0.f, lq = 0.f;
    #pragma unroll
    for (int mt = 0; mt < 2; ++mt)
        #pragma unroll
        for (int r = 0; r < 4; ++r) { float v = accA[mt][r]; ls += v; lq += v * v; }
    float mean, istd;
    block_stats(ls, lq, sRed, tid, 1.0f / 2048.0f, mean, istd);
    {
        const int d = wave * 16 + l16;
        #pragma unroll
        for (int mt = 0; mt < 2; ++mt) {
            bf16x4 pk;
            #pragma unroll
            for (int r = 0; r < 4; ++r) {
                float y = (accA[mt][r] - mean) * istd;
                unsigned short u = f2b(y > 0.f ? y : 0.f);
                pk[r] = (short)u;
                vRM[mt * 16 + quad * 4 + r][d] = (short)u;
            }
            *(bf16x4*)(&vT[d][mt * 16 + quad * 4]) = pk;
        }
    }
    __syncthreads();

    {   // k[i][p] = kw[i]·v[p] + kb
        const int it = wave >> 1, pt = wave & 1;
        f32x4 accK = {};
        #pragma unroll
        for (int ks = 0; ks < 64; ks += 32) {
            bf16x8 a = *(const bf16x8*)(&kw[it * 16 + l16][ks + quad * 8]);
            bf16x8 b = *(const bf16x8*)(&vRM[pt * 16 + l16][ks + quad * 8]);
            accK = __builtin_amdgcn_mfma_f32_16x16x32_bf16(a, b, accK, 0, 0, 0);
        }
        bf16x4 pk;
        #pragma unroll
        for (int r = 0; r < 4; ++r)
            pk[r] = (short)f2b(accK[r] + sKB[it * 16 + quad * 4 + r]);
        *(bf16x4*)(&kT[pt * 16 + l16][it * 16 + quad * 4]) = pk;
    }
    __syncthreads();

    if (wave < 2) {   // logits + softmax
        f32x4 accL[2] = {};
        bf16x8 a = *(const bf16x8*)(&sQ[wave * 16 + l16][quad * 8]);
        #pragma unroll
        for (int pt = 0; pt < 2; ++pt) {
            bf16x8 b = *(const bf16x8*)(&kT[pt * 16 + l16][quad * 8]);
            accL[pt] = __builtin_amdgcn_mfma_f32_16x16x32_bf16(a, b, accL[pt], 0, 0, 0);
        }
        #pragma unroll
        for (int r = 0; r < 4; ++r) {
            float a0 = accL[0][r] * 0.125f, a1 = accL[1][r] * 0.125f;
            float mx = fmaxf(a0, a1);
            #pragma unroll
            for (int m = 1; m < 16; m <<= 1) mx = fmaxf(mx, __shfl_xor(mx, m, 64));
            a0 = __expf(a0 - mx); a1 = __expf(a1 - mx);
            float sum = a0 + a1;
            #pragma unroll
            for (int m = 1; m < 16; m <<= 1) sum += __shfl_xor(sum, m, 64);
            const float inv_s = 1.0f / sum;
            const int o = wave * 16 + quad * 4 + r;
            sSC[o][l16]      = (short)f2b(a0 * inv_s);
            sSC[o][16 + l16] = (short)f2b(a1 * inv_s);
        }
    }
    __syncthreads();

    f32x4 accB[2] = {};
    {
        bf16x8 b = *(const bf16x8*)(&vT[wave * 16 + l16][quad * 8]);
        #pragma unroll
        for (int mt = 0; mt < 2; ++mt) {
            bf16x8 a = *(const bf16x8*)(&sSC[mt * 16 + l16][quad * 8]);
            accB[mt] = __builtin_amdgcn_mfma_f32_16x16x32_bf16(a, b, accB[mt], 0, 0, 0);
        }
    }
    ls = 0.f; lq = 0.f;
    #pragma unroll
    for (int mt = 0; mt < 2; ++mt)
        #pragma unroll
        for (int r = 0; r < 4; ++r) { float v = accB[mt][r]; ls += v; lq += v * v; }
    block_stats(ls, lq, sRed, tid, 1.0f / 2048.0f, mean, istd);

    const int d = wave * 16 + l16;
    #pragma unroll
    for (int mt = 0; mt < 2; ++mt)
        #pragma unroll
        for (int r = 0; r < 4; ++r) {
            float y = (accB[mt][r] - mean) * istd;
            outp[(mt * 16 + quad * 4 + r) * 64 + d] = f2b(y > 0.f ? y : 0.f);
        }
}

__device__ __forceinline__ void p2_stage_cls(
    const unsigned short* Y2row, const float* kwp, const float* kbp, int g,
    short (*kw)[72], short (*sQ)[40], float* sKB, int tid)
{
    {
        const float* kp = kwp + (size_t)g * 2048 + tid * 8;
        float4 x0 = ((const float4*)kp)[0];
        float4 x1 = ((const float4*)kp)[1];
        bf16x8 v;
        v[0]=(short)f2b(x0.x); v[1]=(short)f2b(x0.y); v[2]=(short)f2b(x0.z); v[3]=(short)f2b(x0.w);
        v[4]=(short)f2b(x1.x); v[5]=(short)f2b(x1.y); v[6]=(short)f2b(x1.z); v[7]=(short)f2b(x1.w);
        *(bf16x8*)(&kw[tid >> 3][(tid & 7) * 8]) = v;
    }
    p2_stage_32x32(Y2row + 16384 + g * 1024, sQ, tid);
    if (tid < 32) sKB[tid] = kbp[g * 32 + tid];
}

// ---------------------------------------------------------------------------
// p2 split kernels (small-ws path)
// ---------------------------------------------------------------------------
__global__ __launch_bounds__(256) void p2_reg_kernel(
    const float* __restrict__ feats, const unsigned short* __restrict__ Y1,
    unsigned short* __restrict__ FMS)
{
    const int t = blockIdx.x, g = blockIdx.y;
    const int tid = threadIdx.x;
    __shared__ short fB[32][72];
    __shared__ short Mt[64][72];
    __shared__ short sS[32][40];
    __shared__ short X1T[64][40];
    __shared__ float sRed[16];

    p2_stage_feats(feats + (size_t)(t * NG + g) * 2048, fB, tid);
    p2_stage_64x64(Y1 + (size_t)t * 20480 + g * 4096, Mt, tid);
    p2_stage_32x32(Y1 + (size_t)t * 20480 + 16384 + g * 1024, sS, tid);
    __syncthreads();
    p2_reg_body(fB, Mt, sS, X1T, sRed, FMS + (size_t)t * 8192 + g * 2048, tid);
}

__global__ __launch_bounds__(256) void p2_cls_kernel(
    const float* __restrict__ feats, const unsigned short* __restrict__ Y2,
    const float* __restrict__ kwp, const float* __restrict__ kbp,
    unsigned short* __restrict__ FC)
{
    const int t = blockIdx.x, g = blockIdx.y;
    const int tid = threadIdx.x;
    __shared__ short fB[32][72];
    __shared__ short Vt[64][72];
    __shared__ short kw[32][72];
    __shared__ short vRM[32][72];
    __shared__ short vT[64][40];
    __shared__ short kT[32][40];
    __shared__ short sQ[32][40];
    __shared__ short sSC[32][40];
    __shared__ float sKB[32];
    __shared__ float sRed[16];

    p2_stage_feats(feats + (size_t)(t * NG + g) * 2048, fB, tid);
    p2_stage_64x64(Y2 + (size_t)t * 20480 + g * 4096, Vt, tid);
    p2_stage_cls(Y2 + (size_t)t * 20480, kwp, kbp, g, kw, sQ, sKB, tid);
    __syncthreads();
    p2_cls_body(fB, Vt, kw, vRM, vT, kT, sQ, sSC, sKB, sRed,
                FC + (size_t)t * 8192 + g * 2048, tid);
}

// ---------------------------------------------------------------------------
// p2 fused kernel (big-ws path) — R14: 28.9KB LDS, 1-barrier stats, full
// register prefetch of all global inputs.
// ---------------------------------------------------------------------------
__global__ __launch_bounds__(256, 5) void p2_fused_kernel(
    const float* __restrict__ feats,
    const unsigned short* __restrict__ Y1,
    const unsigned short* __restrict__ Y2,
    const float* __restrict__ kwp, const float* __restrict__ kbp,
    unsigned short* __restrict__ FMS, unsigned short* __restrict__ FC)
{
    const int t = blockIdx.x, g = blockIdx.y;
    const int tid = threadIdx.x;
    const int wave = tid >> 6, lane = tid & 63;
    const int l16 = lane & 15, quad = lane >> 4;

    __shared__ short fB[32][72];     // feats ; then kw
    __shared__ short MtVt[64][72];   // M ; then V
    __shared__ short XvT[64][40];    // X1T ; then vT
    __shared__ short sSQ[32][40];    // S ; then Q
    __shared__ short vRM[32][72];    // v row-major ; then softmax scores
    __shared__ short kT[32][40];
    __shared__ float sKB[32];
    __shared__ float sRed[16];
    short (*sSC)[72] = vRM;          // alias: scores after vRM is dead

    // ---- issue ALL global loads up-front (T14) ----
    const float* fp = feats + (size_t)(t * NG + g) * 2048 + tid * 8;
    float4 f0 = ((const float4*)fp)[0];
    float4 f1 = ((const float4*)fp)[1];
    const unsigned short* y1m = Y1 + (size_t)t * 20480 + g * 4096 + tid * 16;
    bf16x8 m0 = ((const bf16x8*)y1m)[0];
    bf16x8 m1 = ((const bf16x8*)y1m)[1];
    bf16x4 s0 = *(const bf16x4*)(Y1 + (size_t)t * 20480 + 16384 + g * 1024 + tid * 4);
    const unsigned short* y2v = Y2 + (size_t)t * 20480 + g * 4096 + tid * 16;
    bf16x8 v0 = ((const bf16x8*)y2v)[0];
    bf16x8 v1 = ((const bf16x8*)y2v)[1];
    bf16x4 q0 = *(const bf16x4*)(Y2 + (size_t)t * 20480 + 16384 + g * 1024 + tid * 4);
    const float* kp = kwp + (size_t)g * 2048 + tid * 8;
    float4 k0 = ((const float4*)kp)[0];
    float4 k1 = ((const float4*)kp)[1];
    float kbv = (tid < 32) ? kbp[g * 32 + tid] : 0.f;

    // kw fp32 -> bf16 early (frees 4 VGPRs)
    bf16x8 kwv;
    kwv[0]=(short)f2b(k0.x); kwv[1]=(short)f2b(k0.y); kwv[2]=(short)f2b(k0.z); kwv[3]=(short)f2b(k0.w);
    kwv[4]=(short)f2b(k1.x); kwv[5]=(short)f2b(k1.y); kwv[6]=(short)f2b(k1.z); kwv[7]=(short)f2b(k1.w);

    // ---- stage phase-1 LDS ----
    {
        bf16x8 v;
        v[0]=(short)f2b(f0.x); v[1]=(short)f2b(f0.y); v[2]=(short)f2b(f0.z); v[3]=(short)f2b(f0.w);
        v[4]=(short)f2b(f1.x); v[5]=(short)f2b(f1.y); v[6]=(short)f2b(f1.z); v[7]=(short)f2b(f1.w);
        *(bf16x8*)(&fB[tid >> 3][(tid & 7) * 8]) = v;
    }
    {
        const int d = tid >> 2, c0 = (tid & 3) * 16;
        *(bf16x8*)(&MtVt[d][c0])     = m0;
        *(bf16x8*)(&MtVt[d][c0 + 8]) = m1;
    }
    *(bf16x4*)(&sSQ[tid >> 3][(tid & 7) * 4]) = s0;
    if (tid < 32) sKB[tid] = kbv;
    __syncthreads();

    unsigned short* outR = FMS + (size_t)t * 8192 + g * 2048;
    unsigned short* outC = FC  + (size_t)t * 8192 + g * 2048;
    float mean, istd, ls, lq;

    // ================= reg branch =================
    {
        f32x4 accA[2] = {};
        #pragma unroll
        for (int ks = 0; ks < 64; ks += 32) {
            bf16x8 b = *(const bf16x8*)(&MtVt[wave * 16 + l16][ks + quad * 8]);
            #pragma unroll
            for (int mt = 0; mt < 2; ++mt) {
                bf16x8 a = *(const bf16x8*)(&fB[mt * 16 + l16][ks + quad * 8]);
                accA[mt] = __builtin_amdgcn_mfma_f32_16x16x32_bf16(a, b, accA[mt], 0, 0, 0);
            }
        }
        ls = 0.f; lq = 0.f;
        #pragma unroll
        for (int mt = 0; mt < 2; ++mt)
            #pragma unroll
            for (int r = 0; r < 4; ++r) { float v = accA[mt][r]; ls += v; lq += v * v; }
        block_stats2(ls, lq, sRed, tid, 1.0f / 2048.0f, mean, istd);
        #pragma unroll
        for (int mt = 0; mt < 2; ++mt) {
            bf16x4 pk;
            #pragma unroll
            for (int r = 0; r < 4; ++r) {
                float y = (accA[mt][r] - mean) * istd;
                pk[r] = (short)f2b(y > 0.f ? y : 0.f);
            }
            *(bf16x4*)(&XvT[wave * 16 + l16][mt * 16 + quad * 4]) = pk;
        }
        __syncthreads();

        f32x4 accB[2] = {};
        {
            bf16x8 b = *(const bf16x8*)(&XvT[wave * 16 + l16][quad * 8]);
            #pragma unroll
            for (int mt = 0; mt < 2; ++mt) {
                bf16x8 a = *(const bf16x8*)(&sSQ[mt * 16 + l16][quad * 8]);
                accB[mt] = __builtin_amdgcn_mfma_f32_16x16x32_bf16(a, b, accB[mt], 0, 0, 0);
            }
        }
        ls = 0.f; lq = 0.f;
        #pragma unroll
        for (int mt = 0; mt < 2; ++mt)
            #pragma unroll
            for (int r = 0; r < 4; ++r) { float v = accB[mt][r]; ls += v; lq += v * v; }
        block_stats2(ls, lq, sRed, tid, 1.0f / 2048.0f, mean, istd);
        // after this barrier: MtVt (read in accA) and sSQ (read in accB) are dead
        const int d = wave * 16 + l16;
        #pragma unroll
        for (int mt = 0; mt < 2; ++mt)
            #pragma unroll
            for (int r = 0; r < 4; ++r) {
                float y = (accB[mt][r] - mean) * istd;
                outR[(mt * 16 + quad * 4 + r) * 64 + d] = f2b(y > 0.f ? y : 0.f);
            }
    }

    // ---- stage phase-2 LDS from prefetched regs (no global latency) ----
    {
        const int d = tid >> 2, c0 = (tid & 3) * 16;
        *(bf16x8*)(&MtVt[d][c0])     = v0;
        *(bf16x8*)(&MtVt[d][c0 + 8]) = v1;
    }
    *(bf16x4*)(&sSQ[tid >> 3][(tid & 7) * 4]) = q0;
    __syncthreads();

    // ================= cls branch =================
    {
        f32x4 accA[2] = {};
        #pragma unroll
        for (int ks = 0; ks < 64; ks += 32) {
            bf16x8 b = *(const bf16x8*)(&MtVt[wave * 16 + l16][ks + quad * 8]);
            #pragma unroll
            for (int mt = 0; mt < 2; ++mt) {
                bf16x8 a = *(const bf16x8*)(&fB[mt * 16 + l16][ks + quad * 8]);
                accA[mt] = __builtin_amdgcn_mfma_f32_16x16x32_bf16(a, b, accA[mt], 0, 0, 0);
            }
        }
        ls = 0.f; lq = 0.f;
        #pragma unroll
        for (int mt = 0; mt < 2; ++mt)
            #pragma unroll
            for (int r = 0; r < 4; ++r) { float v = accA[mt][r]; ls += v; lq += v * v; }
        block_stats2(ls, lq, sRed, tid, 1.0f / 2048.0f, mean, istd);
        // after barrier: all fB reads done -> safe to overwrite with kw below
        {
            const int d = wave * 16 + l16;
            #pragma unroll
            for (int mt = 0; mt < 2; ++mt) {
                bf16x4 pk;
                #pragma unroll
                for (int r = 0; r < 4; ++r) {
                    float y = (accA[mt][r] - mean) * istd;
                    unsigned short u = f2b(y > 0.f ? y : 0.f);
                    pk[r] = (short)u;
                    vRM[mt * 16 + quad * 4 + r][d] = (short)u;
                }
                *(bf16x4*)(&XvT[d][mt * 16 + quad * 4]) = pk;
            }
        }
        // stage kw into fB's space (from prefetched regs)
        *(bf16x8*)(&fB[tid >> 3][(tid & 7) * 8]) = kwv;
        __syncthreads();

        {   // k[i][p] = kw[i]·v[p] + kb
            const int it = wave >> 1, pt = wave & 1;
            f32x4 accK = {};
            #pragma unroll
            for (int ks = 0; ks < 64; ks += 32) {
                bf16x8 a = *(const bf16x8*)(&fB[it * 16 + l16][ks + quad * 8]);
                bf16x8 b = *(const bf16x8*)(&vRM[pt * 16 + l16][ks + quad * 8]);
                accK = __builtin_amdgcn_mfma_f32_16x16x32_bf16(a, b, accK, 0, 0, 0);
            }
            bf16x4 pk;
            #pragma unroll
            for (int r = 0; r < 4; ++r)
                pk[r] = (short)f2b(accK[r] + sKB[it * 16 + quad * 4 + r]);
            *(bf16x4*)(&kT[pt * 16 + l16][it * 16 + quad * 4]) = pk;
        }
        __syncthreads();
        // vRM dead from here; sSC (alias) becomes live

        if (wave < 2) {   // logits + softmax
            f32x4 accL[2] = {};
            bf16x8 a = *(const bf16x8*)(&sSQ[wave * 16 + l16][quad * 8]);
            #pragma unroll
            for (int pt = 0; pt < 2; ++pt) {
                bf16x8 b = *(const bf16x8*)(&kT[pt * 16 + l16][quad * 8]);
                accL[pt] = __builtin_amdgcn_mfma_f32_16x16x32_bf16(a, b, accL[pt], 0, 0, 0);
            }
            #pragma unroll
            for (int r = 0; r < 4; ++r) {
                float a0 = accL[0][r] * 0.125f, a1 = accL[1][r] * 0.125f;
                float mx = fmaxf(a0, a1);
                #pragma unroll
                for (int m = 1; m < 16; m <<= 1) mx = fmaxf(mx, __shfl_xor(mx, m, 64));
                a0 = __expf(a0 - mx); a1 = __expf(a1 - mx);
                float sum = a0 + a1;
                #pragma unroll
                for (int m = 1; m < 16; m <<= 1) sum += __shfl_xor(sum, m, 64);
                const float inv_s = 1.0f / sum;
                const int o = wave * 16 + quad * 4 + r;
                sSC[o][l16]      = (short)f2b(a0 * inv_s);
                sSC[o][16 + l16] = (short)f2b(a1 * inv_s);
            }
        }
        __syncthreads();

        f32x4 accB[2] = {};
        {
            bf16x8 b = *(const bf16x8*)(&XvT[wave * 16 + l16][quad * 8]);
            #pragma unroll
            for (int mt = 0; mt < 2; ++mt) {
                bf16x8 a = *(const bf16x8*)(&sSC[mt * 16 + l16][quad * 8]);
                accB[mt] = __builtin_amdgcn_mfma_f32_16x16x32_bf16(a, b, accB[mt], 0, 0, 0);
            }
        }
        ls = 0.f; lq = 0.f;
        #pragma unroll
        for (int mt = 0; mt < 2; ++mt)
            #pragma unroll
            for (int r = 0; r < 4; ++r) { float v = accB[mt][r]; ls += v; lq += v * v; }
        block_stats2(ls, lq, sRed, tid, 1.0f / 2048.0f, mean, istd);

        const int d = wave * 16 + l16;
        #pragma unroll
        for (int mt = 0; mt < 2; ++mt)
            #pragma unroll
            for (int r = 0; r < 4; ++r) {
                float y = (accB[mt][r] - mean) * istd;
                outC[(mt * 16 + quad * 4 + r) * 64 + d] = f2b(y > 0.f ? y : 0.f);
            }
    }
}

// ---------------------------------------------------------------------------
// Final: reduce split-K=8 partials, residual add, affine LN over 256, fp32 out.
// ---------------------------------------------------------------------------
__global__ __launch_bounds__(256) void final_ln_kernel(
    const float* __restrict__ qv,
    const float* __restrict__ MSP, const float* __restrict__ CLP,
    const float* __restrict__ Wv_b, const float* __restrict__ Wv2_b,
    const float* __restrict__ lnA_w, const float* __restrict__ lnA_b,
    const float* __restrict__ lnB_w, const float* __restrict__ lnB_b,
    float* __restrict__ out)
{
    __shared__ float sRed[16];
    const int t = blockIdx.x;
    const int br = blockIdx.y;
    const int c = threadIdx.x;
    const float* P = br ? CLP : MSP;
    const float* bias = br ? Wv2_b : Wv_b;
    const float* lw = br ? lnB_w : lnA_w;
    const float* lb = br ? lnB_b : lnA_b;

    float x = qv[t * 256 + c] + bias[c];
    #pragma unroll
    for (int s = 0; s < 8; ++s) x += P[(size_t)s * (BN * 256) + t * 256 + c];

    float mean, istd;
    block_stats(x, x * x, sRed, c, 1.0f / 256.0f, mean, istd);
    out[(size_t)br * (BN * 256) + t * 256 + c] = (x - mean) * istd * lw[c] + lb[c];
}

// ---------------------------------------------------------------------------
extern "C" void kernel_launch(void* const* d_in, const int* in_sizes, int n_in,
                              void* d_out, int out_size, void* d_ws, size_t ws_size,
                              hipStream_t stream) {
    const float* feats = (const float*)d_in[0];
    const float* qv    = (const float*)d_in[1];
    const float* m_w   = (const float*)d_in[7];
    const float* m_b   = (const float*)d_in[8];
    const float* s_w   = (const float*)d_in[9];
    const float* s_b   = (const float*)d_in[10];
    const float* q_w   = (const float*)d_in[11];
    const float* q_b   = (const float*)d_in[12];
    const float* v_w   = (const float*)d_in[13];
    const float* v_b   = (const float*)d_in[14];
    const float* k_w   = (const float*)d_in[15];
    const float* k_b   = (const float*)d_in[16];
    const float* Wv_w  = (const float*)d_in[17];
    const float* Wv_b  = (const float*)d_in[18];
    const float* Wv2_w = (const float*)d_in[19];
    const float* Wv2_b = (const float*)d_in[20];
    const float* lnA_w = (const float*)d_in[21];
    const float* lnA_b = (const float*)d_in[22];
    const float* lnB_w = (const float*)d_in[23];
    const float* lnB_b = (const float*)d_in[24];

    char* ws = (char*)d_ws;
    const dim3 blk(256);

    if (ws_size >= 275251200ull) {
        // ===== BIG path (275.3 MB) =====
        unsigned short* Y1 = (unsigned short*)(ws);
        unsigned short* Y2 = (unsigned short*)(ws + 98304000);
        unsigned short* W1   = (unsigned short*)(ws + 196608000);
        unsigned short* W2   = (unsigned short*)(ws + 196608000 + 10485760);
        unsigned short* qvP  = (unsigned short*)(ws + 196608000 + 20971520);  // 1,245,184 B
        float* b1 = (float*)(ws + 196608000 + 22216704);
        float* b2 = (float*)(ws + 196608000 + 22298624);
        unsigned short* FMS = (unsigned short*)(ws + 196608000);
        unsigned short* FC  = (unsigned short*)(ws + 235929600);
        unsigned short* WvB  = (unsigned short*)(ws + 98304000);
        unsigned short* Wv2B = (unsigned short*)(ws + 98304000 + 4194304);
        float* MSP = (float*)(ws);
        float* CLP = (float*)(ws + 19660800);

        prep_perm_kernel<<<dim3(4096, 2), blk, 0, stream>>>(m_w, m_b, W1, b1,
                                                            v_w, v_b, W2, b2);
        prep_flat_frag_kernel<<<dim3(512, 2), blk, 0, stream>>>(s_w, W1, q_w, W2);
        prep_pack_a_kernel<<<304, blk, 0, stream>>>(qv, qvP);
        copy_bias_kernel<<<dim3(16, 2), blk, 0, stream>>>(s_b, b1 + 16384, q_b, b2 + 16384);
        gemm_gen_kernel<<<dim3(19, 320), blk, 0, stream>>>(
            qvP, W1, b1, Y1, W2, b2, Y2, 160, BN, 20480);
        p2_fused_kernel<<<dim3(BN, NG), blk, 0, stream>>>(
            feats, Y1, Y2, k_w, k_b, FMS, FC);
        prep_flat_kernel<<<dim3(1024, 2), blk, 0, stream>>>(
            Wv_w, WvB, 256 * 8192, Wv2_w, Wv2B, 256 * 8192, nullptr, nullptr, 0);
        gemm_proj_kernel<<<dim3(38, 4, 16), blk, 0, stream>>>(
            FMS, WvB, MSP, FC, Wv2B, CLP, 8, BN, 256, 8192, 1024);
        final_ln_kernel<<<dim3(BN, 2), blk, 0, stream>>>(
            qv, MSP, CLP, Wv_b, Wv2_b, lnA_w, lnA_b, lnB_w, lnB_b, (float*)d_out);
    } else {
        // ===== SMALL path (176.9 MB fallback) =====
        unsigned short* Y1  = (unsigned short*)(ws);
        unsigned short* FMS = (unsigned short*)(ws + 98304000);
        unsigned short* FC  = (unsigned short*)(ws + 137625600);
        unsigned short* W1   = (unsigned short*)(ws + 137625600);
        unsigned short* W2   = (unsigned short*)(ws + 137625600 + 10485760);
        unsigned short* qvP  = (unsigned short*)(ws + 137625600 + 20971520);
        float* b1 = (float*)(ws + 137625600 + 22216704);
        float* b2 = (float*)(ws + 137625600 + 22298624);
        float* MSP = (float*)(ws);
        float* CLP = (float*)(ws + 19660800);
        unsigned short* WvB  = (unsigned short*)(ws + 39321600);
        unsigned short* Wv2B = (unsigned short*)(ws + 43515904);

        prep_perm_kernel<<<dim3(4096, 2), blk, 0, stream>>>(m_w, m_b, W1, b1,
                                                            v_w, v_b, W2, b2);
        prep_flat_frag_kernel<<<dim3(512, 2), blk, 0, stream>>>(s_w, W1, q_w, W2);
        prep_pack_a_kernel<<<304, blk, 0, stream>>>(qv, qvP);
        copy_bias_kernel<<<dim3(16, 2), blk, 0, stream>>>(s_b, b1 + 16384, q_b, b2 + 16384);
        gemm_gen_kernel<<<dim3(19, 160), blk, 0, stream>>>(
            qvP, W1, b1, Y1, W1, b1, Y1, 160, BN, 20480);
        p2_reg_kernel<<<dim3(BN, NG), blk, 0, stream>>>(feats, Y1, FMS);
        gemm_gen_kernel<<<dim3(19, 160), blk, 0, stream>>>(
            qvP, W2, b2, Y1, W2, b2, Y1, 160, BN, 20480);
        p2_cls_kernel<<<dim3(BN, NG), blk, 0, stream>>>(feats, Y1, k_w, k_b, FC);
        prep_flat_kernel<<<dim3(1024, 2), blk, 0, stream>>>(
            Wv_w, WvB, 256 * 8192, Wv2_w, Wv2B, 256 * 8192, nullptr, nullptr, 0);
        gemm_proj_kernel<<<dim3(38, 4, 8), blk, 0, stream>>>(
            FMS, WvB, MSP, FMS, WvB, MSP, 8, BN, 256, 8192, 1024);
        gemm_proj_kernel<<<dim3(38, 4, 8), blk, 0, stream>>>(
            FC, Wv2B, CLP, FC, Wv2B, CLP, 8, BN, 256, 8192, 1024);
        final_ln_kernel<<<dim3(BN, 2), blk, 0, stream>>>(
            qv, MSP, CLP, Wv_b, Wv2_b, lnA_w, lnA_b, lnB_w, lnB_b, (float*)d_out);
    }
}